// Round 18
// baseline (396.196 us; speedup 1.0000x reference)
//
#include <hip/hip_runtime.h>
#include <hip/hip_cooperative_groups.h>
#include <math.h>

// Mamba block forward, l-major activations [b, l, d].
// B=4, DIM=256, L=4096, D_INNER=512, D_STATE=16, DT_RANK=16, D_CONV=4.
// R19: occupancy-adaptive cooperative mega-kernel (grid-stride phases; grid
// sized at runtime from hipOccupancyMaxActiveBlocksPerMultiprocessor --
// R18's fixed grid=512 was rejected when occupancy < 2/CU). Fallback to the
// R16 7-kernel pipeline if cooperative launch unsupported (host-query
// decision only; deterministic, capture-safe).

namespace cg = cooperative_groups;

namespace {
constexpr int kB   = 4;
constexpr int kDim = 256;
constexpr int kL   = 4096;
constexpr int kDI  = 512;
constexpr int kN   = 16;
constexpr int kNC  = 64;   // scan chunks
constexpr int kCS  = 64;   // chunk size
} // namespace

typedef __attribute__((ext_vector_type(8))) short bf16x8;
typedef __attribute__((ext_vector_type(4))) float f32x4;
typedef __attribute__((ext_vector_type(2))) float f32x2;

__device__ __forceinline__ float rcpf(float x) { return __builtin_amdgcn_rcpf(x); }
__device__ __forceinline__ float siluf(float x) { return x * rcpf(1.f + __expf(-x)); }
__device__ __forceinline__ float softplusf(float x) {
  return fmaxf(x, 0.f) + __logf(1.f + __expf(-fabsf(x)));
}

__device__ __forceinline__ unsigned short f2bf(float x) {
  union { float f; unsigned int u; } v; v.f = x;
  unsigned int u = v.u;
  u += 0x7fffu + ((u >> 16) & 1u);   // RNE
  return (unsigned short)(u >> 16);
}
__device__ __forceinline__ float bf2f(unsigned short u) {
  union { unsigned int i; float f; } v; v.i = ((unsigned int)u) << 16; return v.f;
}

__device__ __forceinline__ void gload_lds16(const void* g, void* l) {
  __builtin_amdgcn_global_load_lds(
      (const __attribute__((address_space(1))) unsigned int*)g,
      (__attribute__((address_space(3))) unsigned int*)l, 16, 0, 0);
}

// ===========================================================================
// Fallback path: R16 kernels (verbatim; passing at 131.7 us).
// ===========================================================================
__global__ __launch_bounds__(256) void k_prep(const float* __restrict__ w_in,
                                              const float* __restrict__ w_out,
                                              const float* __restrict__ w_x,
                                              const float* __restrict__ w_dt,
                                              const float* __restrict__ A_log,
                                              const float* __restrict__ x,
                                              unsigned short* __restrict__ wib,
                                              unsigned short* __restrict__ wob,
                                              unsigned short* __restrict__ wxb,
                                              unsigned short* __restrict__ wdtb,
                                              float* __restrict__ Avz,
                                              unsigned int* __restrict__ flagA,
                                              unsigned short* __restrict__ xt) {
  __shared__ float Xs[64][65];
  const int blk = blockIdx.x;
  const int t = threadIdx.x;
  if (blk < 1760) {
    int idx = blk * 256 + t;
    if (idx < 262144) wib[idx] = f2bf(w_in[idx]);
    else if (idx < 393216) wob[idx - 262144] = f2bf(w_out[idx - 262144]);
    else if (idx < 417792) wxb[idx - 393216] = f2bf(w_x[idx - 393216]);
    else {
      int i = idx - 417792;
      int r = i & 31, d = i >> 5;
      wdtb[i] = (r < 16) ? f2bf(w_dt[d * 16 + r]) : (unsigned short)0;
    }
  } else if (blk < 1762) {
    int d = (blk - 1760) * 256 + t;
    float a0 = -__expf(A_log[d * kN]);
    bool ok = true;
#pragma unroll
    for (int n = 1; n < kN; ++n) {
      float av = -__expf(A_log[d * kN + n]);
      ok = ok && (fabsf(av - (n + 1) * a0) <= 1e-5f * fabsf(av));
    }
    Avz[d] = a0;
    unsigned long long bal = __ballot(ok);
    int wv = t >> 6;
    if ((t & 63) == 0) ((unsigned long long*)Xs)[wv] = bal;
    __syncthreads();
    if (t == 0) {
      unsigned long long all = ~0ull;
#pragma unroll
      for (int w = 0; w < 4; ++w) all &= ((unsigned long long*)Xs)[w];
      flagA[blk - 1760] = (all == ~0ull) ? 1u : 0u;
    }
  } else {
    int id = blk - 1762;
    int lb = id & 63, db = (id >> 6) & 3, b = id >> 8;
    const int d0 = db * 64, l0 = lb * 64;
    {
      int lq = (t & 15) * 4, dr = t >> 4;
#pragma unroll
      for (int rep = 0; rep < 4; ++rep) {
        int dd = rep * 16 + dr;
        float4 v = *(const float4*)&x[((size_t)b * kDim + d0 + dd) * kL + l0 + lq];
        Xs[dd][lq] = v.x; Xs[dd][lq + 1] = v.y;
        Xs[dd][lq + 2] = v.z; Xs[dd][lq + 3] = v.w;
      }
    }
    __syncthreads();
    {
      int di = (t & 15) * 4, lr = t >> 4;
#pragma unroll
      for (int rep = 0; rep < 4; ++rep) {
        int lj = rep * 16 + lr;
        ushort4 o;
        o.x = f2bf(Xs[di][lj]);     o.y = f2bf(Xs[di + 1][lj]);
        o.z = f2bf(Xs[di + 2][lj]); o.w = f2bf(Xs[di + 3][lj]);
        *(ushort4*)(xt + ((size_t)b * kL + l0 + lj) * kDim + d0 + di) = o;
      }
    }
  }
}

__global__ __launch_bounds__(256) void gemm_in_lm(const unsigned short* __restrict__ xt,
                                                  const unsigned short* __restrict__ W,
                                                  unsigned short* __restrict__ ubf,
                                                  unsigned short* __restrict__ resb) {
  __shared__ __align__(16) unsigned short As[128 * 64];
  __shared__ __align__(16) unsigned short Bs[128 * 64];
  const int e0 = blockIdx.x * 128;
  const int l0 = blockIdx.y * 128;
  const int b  = blockIdx.z;
  const int t  = threadIdx.x;
  const int wave = t >> 6, lane = t & 63;
  const int wm = wave >> 1, wn = wave & 1;
  const unsigned short* Ab = xt + (size_t)b * kL * kDim;

  f32x4 acc[4][4];
#pragma unroll
  for (int i = 0; i < 4; ++i)
#pragma unroll
    for (int j = 0; j < 4; ++j) acc[i][j] = (f32x4)0.0f;

  const int srow = t >> 3, sch = t & 7;
  for (int kt = 0; kt < 4; ++kt) {
    const int k0 = kt * 64;
#pragma unroll
    for (int c = 0; c < 4; ++c) {
      int row = c * 32 + srow;
      int gch = sch ^ (row & 7);
      gload_lds16(Ab + (size_t)(l0 + row) * kDim + k0 + gch * 8,
                  (char*)As + c * 4096 + wave * 1024);
      gload_lds16(W  + (size_t)(e0 + row) * kDim + k0 + gch * 8,
                  (char*)Bs + c * 4096 + wave * 1024);
    }
    __syncthreads();
#pragma unroll
    for (int ks = 0; ks < 2; ++ks) {
      bf16x8 af[4], bfr[4];
#pragma unroll
      for (int f = 0; f < 4; ++f) {
        int ra = wm * 64 + f * 16 + (lane & 15);
        int ca = (ks * 4 + (lane >> 4)) ^ (ra & 7);
        af[f] = *(const bf16x8*)((const char*)As + ra * 128 + ca * 16);
        int rb = wn * 64 + f * 16 + (lane & 15);
        int cb = (ks * 4 + (lane >> 4)) ^ (rb & 7);
        bfr[f] = *(const bf16x8*)((const char*)Bs + rb * 128 + cb * 16);
      }
#pragma unroll
      for (int i = 0; i < 4; ++i)
#pragma unroll
        for (int j = 0; j < 4; ++j)
          acc[i][j] = __builtin_amdgcn_mfma_f32_16x16x32_bf16(af[i], bfr[j], acc[i][j], 0, 0, 0);
    }
    __syncthreads();
  }

  const bool is_u = (e0 < kDI);
  unsigned short* dst = is_u ? ubf : resb;
  const int ebase = is_u ? e0 : (e0 - kDI);
#pragma unroll
  for (int i = 0; i < 4; ++i)
#pragma unroll
    for (int j = 0; j < 4; ++j)
#pragma unroll
      for (int r = 0; r < 4; ++r) {
        int l = l0 + wm * 64 + i * 16 + (lane >> 4) * 4 + r;
        int e = ebase + wn * 64 + j * 16 + (lane & 15);
        dst[((size_t)b * kL + l) * kDI + e] = f2bf(acc[i][j][r]);
      }
}

__global__ __launch_bounds__(256) void k_xproj_dt(const unsigned short* __restrict__ Wx,
                                                  const unsigned short* __restrict__ Wdtb,
                                                  const float* __restrict__ bdt,
                                                  const unsigned short* __restrict__ ubf,
                                                  const float* __restrict__ cw,
                                                  const float* __restrict__ cb,
                                                  float* __restrict__ dbcBC,
                                                  unsigned short* __restrict__ ucb,
                                                  unsigned short* __restrict__ delb) {
  __shared__ __align__(16) unsigned short As[64 * 64];
  __shared__ __align__(16) unsigned short Bs[64 * 64];
  __shared__ __align__(16) unsigned short dtTl[64 * 32];
  __shared__ __align__(16) unsigned short Wl[128 * 32];
  const int l0 = blockIdx.x * 64;
  const int b  = blockIdx.y;
  const int t  = threadIdx.x;
  const int wave = t >> 6, lane = t & 63;
  const unsigned short* Ub = ubf + (size_t)b * kL * kDI;

  f32x4 acc[3];
#pragma unroll
  for (int i = 0; i < 3; ++i) acc[i] = (f32x4)0.0f;

  const int srow = t >> 3, sch = t & 7;
  for (int kt = 0; kt < 8; ++kt) {
    const int k0 = kt * 64;
#pragma unroll
    for (int c = 0; c < 2; ++c) {
      int row = c * 32 + srow;
      int grow = row < 48 ? row : 47;
      int gch = sch ^ (row & 7);
      gload_lds16(Wx + (size_t)grow * kDI + k0 + gch * 8,
                  (char*)As + c * 4096 + wave * 1024);
    }
#pragma unroll
    for (int c = 0; c < 2; ++c) {
      int row = c * 32 + srow;
      int gch = sch ^ (row & 7);
      int gl = l0 + row;
      int d0 = k0 + gch * 8;
      const unsigned short* base = Ub + (size_t)gl * kDI + d0;
      uint4 zero4 = make_uint4(0, 0, 0, 0);
      uint4 c0v = *(const uint4*)base;
      uint4 c1v = (gl >= 1) ? *(const uint4*)(base - kDI)     : zero4;
      uint4 c2v = (gl >= 2) ? *(const uint4*)(base - 2 * kDI) : zero4;
      uint4 c3v = (gl >= 3) ? *(const uint4*)(base - 3 * kDI) : zero4;
      const unsigned int* p0 = (const unsigned int*)&c0v;
      const unsigned int* p1 = (const unsigned int*)&c1v;
      const unsigned int* p2 = (const unsigned int*)&c2v;
      const unsigned int* p3 = (const unsigned int*)&c3v;
      unsigned short ov[8];
#pragma unroll
      for (int cc = 0; cc < 8; ++cc) {
        int q = cc >> 1, hi = cc & 1;
        float u0 = bf2f((unsigned short)(hi ? (p0[q] >> 16) : (p0[q] & 0xffff)));
        float u1 = bf2f((unsigned short)(hi ? (p1[q] >> 16) : (p1[q] & 0xffff)));
        float u2 = bf2f((unsigned short)(hi ? (p2[q] >> 16) : (p2[q] & 0xffff)));
        float u3 = bf2f((unsigned short)(hi ? (p3[q] >> 16) : (p3[q] & 0xffff)));
        float4 w = *(const float4*)(cw + (d0 + cc) * 4);
        float a = cb[d0 + cc] + w.x * u3 + w.y * u2 + w.z * u1 + w.w * u0;
        ov[cc] = f2bf(siluf(a));
      }
      *(uint4*)((char*)Bs + c * 4096 + t * 16) = *(const uint4*)ov;
      *(uint4*)(ucb + ((size_t)b * kL + gl) * kDI + d0) = *(const uint4*)ov;
    }
    __syncthreads();
#pragma unroll
    for (int ks = 0; ks < 2; ++ks) {
      bf16x8 af[3], bfr;
#pragma unroll
      for (int f = 0; f < 3; ++f) {
        int ra = f * 16 + (lane & 15);
        int ca = (ks * 4 + (lane >> 4)) ^ (ra & 7);
        af[f] = *(const bf16x8*)((const char*)As + ra * 128 + ca * 16);
      }
      int rb = wave * 16 + (lane & 15);
      int cbk = (ks * 4 + (lane >> 4)) ^ (rb & 7);
      bfr = *(const bf16x8*)((const char*)Bs + rb * 128 + cbk * 16);
#pragma unroll
      for (int i = 0; i < 3; ++i)
        acc[i] = __builtin_amdgcn_mfma_f32_16x16x32_bf16(af[i], bfr, acc[i], 0, 0, 0);
    }
    __syncthreads();
  }

#pragma unroll
  for (int i = 1; i < 3; ++i)
#pragma unroll
    for (int r = 0; r < 4; ++r) {
      int m = i * 16 + (lane >> 4) * 4 + r;
      int l = l0 + wave * 16 + (lane & 15);
      dbcBC[((size_t)b * 32 + (m - 16)) * kL + l] = acc[i][r];
    }
  {
    int lloc = wave * 16 + (lane & 15);
    int m0 = (lane >> 4) * 4;
    ushort4 v;
    v.x = f2bf(acc[0][0]); v.y = f2bf(acc[0][1]);
    v.z = f2bf(acc[0][2]); v.w = f2bf(acc[0][3]);
    int byte = lloc * 64 + (((m0 >> 3) ^ (lloc & 3)) << 4) + ((m0 & 7) << 1);
    *(ushort4*)((char*)dtTl + byte) = v;
  }
  if (t < 128) {
    int lz = t >> 1, zc = 2 + (t & 1);
    *(uint4*)((char*)dtTl + lz * 64 + ((zc ^ (lz & 3)) << 4)) = make_uint4(0, 0, 0, 0);
  }
  __syncthreads();

  for (int dt4 = 0; dt4 < 4; ++dt4) {
#pragma unroll
    for (int c2 = 0; c2 < 2; ++c2) {
      int unit = c2 * 256 + t;
      int row = unit >> 2, sc = unit & 3;
      int gch = sc ^ (row & 3);
      gload_lds16(Wdtb + (size_t)(dt4 * 128 + row) * 32 + gch * 8,
                  (char*)Wl + c2 * 4096 + t * 16);
    }
    __syncthreads();
    f32x4 acc2[4][2];
#pragma unroll
    for (int i = 0; i < 4; ++i)
#pragma unroll
      for (int j = 0; j < 2; ++j) acc2[i][j] = (f32x4)0.0f;
    bf16x8 afr[4], bfr2[2];
#pragma unroll
    for (int f = 0; f < 4; ++f) {
      int ra = f * 16 + (lane & 15);
      afr[f] = *(const bf16x8*)((const char*)dtTl + ra * 64 + (((lane >> 4) ^ (ra & 3)) << 4));
    }
#pragma unroll
    for (int f = 0; f < 2; ++f) {
      int rb = wave * 32 + f * 16 + (lane & 15);
      bfr2[f] = *(const bf16x8*)((const char*)Wl + rb * 64 + (((lane >> 4) ^ (rb & 3)) << 4));
    }
#pragma unroll
    for (int i = 0; i < 4; ++i)
#pragma unroll
      for (int j = 0; j < 2; ++j)
        acc2[i][j] = __builtin_amdgcn_mfma_f32_16x16x32_bf16(afr[i], bfr2[j], acc2[i][j], 0, 0, 0);
#pragma unroll
    for (int j = 0; j < 2; ++j) {
      int d = dt4 * 128 + wave * 32 + j * 16 + (lane & 15);
      float bd = bdt[d];
#pragma unroll
      for (int i = 0; i < 4; ++i)
#pragma unroll
        for (int r = 0; r < 4; ++r) {
          int l = l0 + i * 16 + (lane >> 4) * 4 + r;
          float delta = softplusf(acc2[i][j][r] + bd);
          delb[((size_t)b * kL + l) * kDI + d] = f2bf(delta);
        }
    }
    __syncthreads();
  }
}

__global__ __launch_bounds__(128) void k_scanA(const unsigned short* __restrict__ delb,
                                               const unsigned short* __restrict__ ucb,
                                               const float* __restrict__ dbcBC,
                                               const float* __restrict__ A_log,
                                               const float* __restrict__ Avz,
                                               const unsigned int* __restrict__ flagA,
                                               float* __restrict__ Pprod,
                                               float* __restrict__ Pfull,
                                               float* __restrict__ S) {
  __shared__ __align__(16) float Bsh[16][kCS];
  const int b = blockIdx.z, ch = blockIdx.y;
  const int t = threadIdx.x;
  const int d = blockIdx.x * 128 + t;
  const int l0 = ch * kCS;
  {
    int row = t >> 3, li = (t & 7) * 8;
    *(float4*)&Bsh[row][li] =
        *(const float4*)&dbcBC[((size_t)b * 32 + row) * kL + l0 + li];
    *(float4*)&Bsh[row][li + 4] =
        *(const float4*)&dbcBC[((size_t)b * 32 + row) * kL + l0 + li + 4];
  }
  __syncthreads();
  const bool fast = (flagA[0] != 0u) && (flagA[1] != 0u);
  const float Av0 = Avz[d];
  const unsigned short* pDel = delb + ((size_t)b * kL + l0) * kDI + d;
  const unsigned short* pU = ucb + ((size_t)b * kL + l0) * kDI + d;
  size_t obase = (size_t)(b * kNC + ch) * (kN * kDI) + d;

  if (fast) {
    f32x2 Sv2[8];
#pragma unroll
    for (int m = 0; m < 8; ++m) Sv2[m] = (f32x2){0.f, 0.f};
    float Pp = 1.f;
    for (int i = 0; i < kCS; i += 4) {
      f32x2 a2[4], e2[4], du2[4];
#pragma unroll
      for (int jj = 0; jj < 4; ++jj) {
        float dl = bf2f(pDel[(size_t)(i + jj) * kDI]);
        float uu = bf2f(pU[(size_t)(i + jj) * kDI]);
        float E = __expf(dl * Av0);
        float duv = dl * uu;
        du2[jj] = (f32x2){duv, duv};
        float Esq = E * E;
        a2[jj] = (f32x2){E, Esq};
        e2[jj] = (f32x2){Esq, Esq};
        Pp *= E;
      }
#pragma unroll
      for (int m = 0; m < 8; ++m) {
        float4 Ba = *(const float4*)&Bsh[2 * m][i];
        float4 Bb = *(const float4*)&Bsh[2 * m + 1][i];
        Sv2[m] = Sv2[m] * a2[0] + du2[0] * (f32x2){Ba.x, Bb.x};
        Sv2[m] = Sv2[m] * a2[1] + du2[1] * (f32x2){Ba.y, Bb.y};
        Sv2[m] = Sv2[m] * a2[2] + du2[2] * (f32x2){Ba.z, Bb.z};
        Sv2[m] = Sv2[m] * a2[3] + du2[3] * (f32x2){Ba.w, Bb.w};
        if (m < 7) {
          a2[0] *= e2[0]; a2[1] *= e2[1]; a2[2] *= e2[2]; a2[3] *= e2[3];
        }
      }
    }
    Pprod[(size_t)(b * kNC + ch) * kDI + d] = Pp;
#pragma unroll
    for (int n = 0; n < kN; ++n)
      S[obase + (size_t)n * kDI] = (n & 1) ? Sv2[n >> 1].y : Sv2[n >> 1].x;
  } else {
    float Av[16];
#pragma unroll
    for (int n = 0; n < kN; ++n) Av[n] = -__expf(A_log[d * kN + n]);
    float Pv[16], Sv[16];
#pragma unroll
    for (int n = 0; n < kN; ++n) { Pv[n] = 1.f; Sv[n] = 0.f; }
    for (int i = 0; i < kCS; i += 4) {
      float del[4], du[4];
#pragma unroll
      for (int jj = 0; jj < 4; ++jj) {
        del[jj] = bf2f(pDel[(size_t)(i + jj) * kDI]);
        du[jj] = del[jj] * bf2f(pU[(size_t)(i + jj) * kDI]);
      }
#pragma unroll
      for (int n = 0; n < kN; ++n) {
        float4 B4 = *(const float4*)&Bsh[n][i];
        float a;
        a = __expf(del[0] * Av[n]); Pv[n] *= a; Sv[n] = Sv[n] * a + du[0] * B4.x;
        a = __expf(del[1] * Av[n]); Pv[n] *= a; Sv[n] = Sv[n] * a + du[1] * B4.y;
        a = __expf(del[2] * Av[n]); Pv[n] *= a; Sv[n] = Sv[n] * a + du[2] * B4.z;
        a = __expf(del[3] * Av[n]); Pv[n] *= a; Sv[n] = Sv[n] * a + du[3] * B4.w;
      }
    }
#pragma unroll
    for (int n = 0; n < kN; ++n) {
      Pfull[obase + (size_t)n * kDI] = Pv[n];
      S[obase + (size_t)n * kDI] = Sv[n];
    }
  }
}

__global__ __launch_bounds__(64) void k_scanB(const float* __restrict__ Pprod,
                                              const float* __restrict__ Pfull,
                                              const float* __restrict__ S,
                                              const unsigned int* __restrict__ flagA,
                                              float* __restrict__ init) {
  int idx = blockIdx.x * 64 + threadIdx.x;
  int b = idx >> 13, nd = idx & 8191;
  int n = nd >> 9, d = nd & 511;
  size_t base = (size_t)b * kNC * 8192 + nd;
  const bool fast = (flagA[0] != 0u) && (flagA[1] != 0u);
  float carry = 0.f;
  if (fast) {
    size_t pbase = (size_t)b * kNC * kDI + d;
    const int e = n + 1;
    for (int c0 = 0; c0 < kNC; c0 += 8) {
      float p[8], s[8];
#pragma unroll
      for (int j = 0; j < 8; ++j) {
        float pr = Pprod[pbase + (size_t)(c0 + j) * kDI];
        float p2 = pr * pr, p4 = p2 * p2, p8 = p4 * p4;
        float pw = 1.f;
        if (e & 1) pw *= pr;
        if (e & 2) pw *= p2;
        if (e & 4) pw *= p4;
        if (e & 8) pw *= p8;
        if (e & 16) pw *= p8 * p8;
        p[j] = pw;
        s[j] = S[base + (size_t)(c0 + j) * 8192];
      }
#pragma unroll
      for (int j = 0; j < 8; ++j) {
        init[base + (size_t)(c0 + j) * 8192] = carry;
        carry = p[j] * carry + s[j];
      }
    }
  } else {
    for (int c0 = 0; c0 < kNC; c0 += 8) {
      float p[8], s[8];
#pragma unroll
      for (int j = 0; j < 8; ++j) {
        size_t o = base + (size_t)(c0 + j) * 8192;
        p[j] = Pfull[o]; s[j] = S[o];
      }
#pragma unroll
      for (int j = 0; j < 8; ++j) {
        init[base + (size_t)(c0 + j) * 8192] = carry;
        carry = p[j] * carry + s[j];
      }
    }
  }
}

__global__ __launch_bounds__(128) void k_scanC(const unsigned short* __restrict__ delb,
                                               const unsigned short* __restrict__ ucb,
                                               const float* __restrict__ dbcBC,
                                               const float* __restrict__ A_log,
                                               const float* __restrict__ Avz,
                                               const unsigned int* __restrict__ flagA,
                                               const float* __restrict__ init,
                                               const unsigned short* __restrict__ resb,
                                               const float* __restrict__ Dp,
                                               unsigned short* __restrict__ yt) {
  __shared__ __align__(16) float BCsh[32][kCS];
  const int b = blockIdx.z, ch = blockIdx.y;
  const int t = threadIdx.x;
  const int d = blockIdx.x * 128 + t;
  const int l0 = ch * kCS;
  {
    int row = t >> 2, li = (t & 3) * 16;
#pragma unroll
    for (int q = 0; q < 4; ++q)
      *(float4*)&BCsh[row][li + q * 4] =
          *(const float4*)&dbcBC[((size_t)b * 32 + row) * kL + l0 + li + q * 4];
  }
  __syncthreads();
  const bool fast = (flagA[0] != 0u) && (flagA[1] != 0u);
  const float Av0 = Avz[d];
  const float Dv = Dp[d];
  const unsigned short* pDel = delb + ((size_t)b * kL + l0) * kDI + d;
  const unsigned short* pU = ucb + ((size_t)b * kL + l0) * kDI + d;
  const unsigned short* pR = resb + ((size_t)b * kL + l0) * kDI + d;
  unsigned short* pY = yt + ((size_t)b * kL + l0) * kDI + d;
  size_t ibase = (size_t)(b * kNC + ch) * (kN * kDI) + d;

  if (fast) {
    f32x2 s2[8];
#pragma unroll
    for (int m = 0; m < 8; ++m)
      s2[m] = (f32x2){init[ibase + (size_t)(2 * m) * kDI],
                      init[ibase + (size_t)(2 * m + 1) * kDI]};
    for (int i = 0; i < kCS; i += 4) {
      float uv[4];
      f32x2 a2[4], e2[4], du2[4], yacc2[4];
#pragma unroll
      for (int jj = 0; jj < 4; ++jj) {
        float dl = bf2f(pDel[(size_t)(i + jj) * kDI]);
        uv[jj] = bf2f(pU[(size_t)(i + jj) * kDI]);
        float E = __expf(dl * Av0);
        float duv = dl * uv[jj];
        du2[jj] = (f32x2){duv, duv};
        float Esq = E * E;
        a2[jj] = (f32x2){E, Esq};
        e2[jj] = (f32x2){Esq, Esq};
        yacc2[jj] = (f32x2){0.f, 0.f};
      }
#pragma unroll
      for (int m = 0; m < 8; ++m) {
        float4 Ba = *(const float4*)&BCsh[2 * m][i];
        float4 Bb = *(const float4*)&BCsh[2 * m + 1][i];
        float4 Ca = *(const float4*)&BCsh[16 + 2 * m][i];
        float4 Cb = *(const float4*)&BCsh[16 + 2 * m + 1][i];
        s2[m] = s2[m] * a2[0] + du2[0] * (f32x2){Ba.x, Bb.x};
        yacc2[0] = yacc2[0] + s2[m] * (f32x2){Ca.x, Cb.x};
        s2[m] = s2[m] * a2[1] + du2[1] * (f32x2){Ba.y, Bb.y};
        yacc2[1] = yacc2[1] + s2[m] * (f32x2){Ca.y, Cb.y};
        s2[m] = s2[m] * a2[2] + du2[2] * (f32x2){Ba.z, Bb.z};
        yacc2[2] = yacc2[2] + s2[m] * (f32x2){Ca.z, Cb.z};
        s2[m] = s2[m] * a2[3] + du2[3] * (f32x2){Ba.w, Bb.w};
        yacc2[3] = yacc2[3] + s2[m] * (f32x2){Ca.w, Cb.w};
        if (m < 7) {
          a2[0] *= e2[0]; a2[1] *= e2[1]; a2[2] *= e2[2]; a2[3] *= e2[3];
        }
      }
#pragma unroll
      for (int jj = 0; jj < 4; ++jj) {
        float yv = yacc2[jj].x + yacc2[jj].y;
        float r = bf2f(pR[(size_t)(i + jj) * kDI]);
        float gv = (yv + uv[jj] * Dv) * siluf(r);
        pY[(size_t)(i + jj) * kDI] = f2bf(gv);
      }
    }
  } else {
    float Av[16];
#pragma unroll
    for (int n = 0; n < kN; ++n) Av[n] = -__expf(A_log[d * kN + n]);
    float s[16];
#pragma unroll
    for (int n = 0; n < kN; ++n) s[n] = init[ibase + (size_t)n * kDI];
    for (int i = 0; i < kCS; i += 4) {
      float uv[4], du[4], del[4], yacc[4] = {0.f, 0.f, 0.f, 0.f};
#pragma unroll
      for (int jj = 0; jj < 4; ++jj) {
        del[jj] = bf2f(pDel[(size_t)(i + jj) * kDI]);
        uv[jj] = bf2f(pU[(size_t)(i + jj) * kDI]);
        du[jj] = del[jj] * uv[jj];
      }
#pragma unroll
      for (int n = 0; n < kN; ++n) {
        float4 B4 = *(const float4*)&BCsh[n][i];
        float4 C4 = *(const float4*)&BCsh[16 + n][i];
        float a;
        a = __expf(del[0] * Av[n]); s[n] = s[n] * a + du[0] * B4.x; yacc[0] += s[n] * C4.x;
        a = __expf(del[1] * Av[n]); s[n] = s[n] * a + du[1] * B4.y; yacc[1] += s[n] * C4.y;
        a = __expf(del[2] * Av[n]); s[n] = s[n] * a + du[2] * B4.z; yacc[2] += s[n] * C4.z;
        a = __expf(del[3] * Av[n]); s[n] = s[n] * a + du[3] * B4.w; yacc[3] += s[n] * C4.w;
      }
#pragma unroll
      for (int jj = 0; jj < 4; ++jj) {
        float r = bf2f(pR[(size_t)(i + jj) * kDI]);
        float gv = (yacc[jj] + uv[jj] * Dv) * siluf(r);
        pY[(size_t)(i + jj) * kDI] = f2bf(gv);
      }
    }
  }
}

__global__ __launch_bounds__(256) void gemm_out(const unsigned short* __restrict__ A,
                                                const unsigned short* __restrict__ Bt,
                                                float* __restrict__ C0) {
  __shared__ __align__(16) unsigned short As[128 * 64];
  __shared__ __align__(16) unsigned short Bs[128 * 64];
  const int n0 = blockIdx.x * 128;
  const int m0 = blockIdx.y * 128;
  const int b  = blockIdx.z;
  const int t  = threadIdx.x;
  const int wave = t >> 6, lane = t & 63;
  const int wm = wave >> 1, wn = wave & 1;
  const unsigned short* Bb = Bt + (size_t)b * kL * kDI;

  f32x4 acc[4][4];
#pragma unroll
  for (int i = 0; i < 4; ++i)
#pragma unroll
    for (int j = 0; j < 4; ++j) acc[i][j] = (f32x4)0.0f;

  const int srow = t >> 3, sch = t & 7;
  for (int kt = 0; kt < 8; ++kt) {
    const int k0 = kt * 64;
#pragma unroll
    for (int c = 0; c < 4; ++c) {
      int row = c * 32 + srow;
      int gch = sch ^ (row & 7);
      gload_lds16(A  + (size_t)(m0 + row) * kDI + k0 + gch * 8,
                  (char*)As + c * 4096 + wave * 1024);
      gload_lds16(Bb + (size_t)(n0 + row) * kDI + k0 + gch * 8,
                  (char*)Bs + c * 4096 + wave * 1024);
    }
    __syncthreads();
#pragma unroll
    for (int ks = 0; ks < 2; ++ks) {
      bf16x8 af[4], bfr[4];
#pragma unroll
      for (int f = 0; f < 4; ++f) {
        int ra = wm * 64 + f * 16 + (lane & 15);
        int ca = (ks * 4 + (lane >> 4)) ^ (ra & 7);
        af[f] = *(const bf16x8*)((const char*)As + ra * 128 + ca * 16);
        int rb = wn * 64 + f * 16 + (lane & 15);
        int cb = (ks * 4 + (lane >> 4)) ^ (rb & 7);
        bfr[f] = *(const bf16x8*)((const char*)Bs + rb * 128 + cb * 16);
      }
#pragma unroll
      for (int i = 0; i < 4; ++i)
#pragma unroll
        for (int j = 0; j < 4; ++j)
          acc[i][j] = __builtin_amdgcn_mfma_f32_16x16x32_bf16(af[i], bfr[j], acc[i][j], 0, 0, 0);
    }
    __syncthreads();
  }
#pragma unroll
  for (int i = 0; i < 4; ++i)
#pragma unroll
    for (int j = 0; j < 4; ++j)
#pragma unroll
      for (int r = 0; r < 4; ++r) {
        int m = m0 + wm * 64 + i * 16 + (lane >> 4) * 4 + r;
        int n = n0 + wn * 64 + j * 16 + (lane & 15);
        C0[((size_t)b * kDim + m) * kL + n] = acc[i][j][r];
      }
}

// ===========================================================================
// Mega path: cooperative kernel with grid-stride phases.
// ===========================================================================
struct MegaArgs {
  const float* x;
  const float* w_in;
  const float* cw;
  const float* cb;
  const float* w_x;
  const float* w_dt;
  const float* bdt;
  const float* A_log;
  const float* Dp;
  const float* w_out;
  float* out;
  float* dbcBC;
  float* Sb;
  float* initb;
  float* Pprodb;
  unsigned short* ubf;
  unsigned short* ucb;
  unsigned short* resb;
  unsigned short* delb;
  unsigned short* wib;
  unsigned short* wob;
  unsigned short* wxb;
  unsigned short* wdtb;
  unsigned short* dtT;
  float* Avz;
  unsigned int* flagA;
  unsigned short* xt;
  float* Pfull;
  unsigned short* yt;
};

union SMem {
  struct { unsigned short As[128 * 64]; unsigned short Bs[128 * 64]; } gin;
  struct { unsigned short As[64 * 64];  unsigned short Bs[32 * 64];  } xp;
  struct { unsigned short As[128 * 32]; unsigned short Bs[128 * 32]; } gdt;
  struct { float Bsh[16][kCS]; } sa;
  struct { float BCsh[32][kCS]; } sc;
  struct { unsigned short As[64 * 64];  unsigned short Bs[128 * 64]; } go;
  float Xs[64][65];
};

__global__ __launch_bounds__(256, 2) void k_mega(MegaArgs a) {
  __shared__ SMem sm;
  cg::grid_group grid = cg::this_grid();
  const int nblk = gridDim.x;
  const int t = threadIdx.x;
  const int wave = t >> 6, lane = t & 63;

  // ===== P0: prep
  for (int job = blockIdx.x; job < 2786; job += nblk) {
    __syncthreads();
    if (job < 1760) {
      int idx = job * 256 + t;
      if (idx < 262144) a.wib[idx] = f2bf(a.w_in[idx]);
      else if (idx < 393216) a.wob[idx - 262144] = f2bf(a.w_out[idx - 262144]);
      else if (idx < 417792) a.wxb[idx - 393216] = f2bf(a.w_x[idx - 393216]);
      else {
        int i = idx - 417792;
        int r = i & 31, d = i >> 5;
        a.wdtb[i] = (r < 16) ? f2bf(a.w_dt[d * 16 + r]) : (unsigned short)0;
      }
    } else if (job < 1762) {
      int d = (job - 1760) * 256 + t;
      float a0 = -__expf(a.A_log[d * kN]);
      bool ok = true;
#pragma unroll
      for (int n = 1; n < kN; ++n) {
        float av = -__expf(a.A_log[d * kN + n]);
        ok = ok && (fabsf(av - (n + 1) * a0) <= 1e-5f * fabsf(av));
      }
      a.Avz[d] = a0;
      unsigned long long bal = __ballot(ok);
      if ((t & 63) == 0) ((unsigned long long*)sm.Xs)[wave] = bal;
      __syncthreads();
      if (t == 0) {
        unsigned long long all = ~0ull;
#pragma unroll
        for (int w = 0; w < 4; ++w) all &= ((unsigned long long*)sm.Xs)[w];
        a.flagA[job - 1760] = (all == ~0ull) ? 1u : 0u;
      }
    } else {
      int id = job - 1762;
      int lb = id & 63, db = (id >> 6) & 3, b = id >> 8;
      const int d0 = db * 64, l0 = lb * 64;
      {
        int lq = (t & 15) * 4, dr = t >> 4;
#pragma unroll
        for (int rep = 0; rep < 4; ++rep) {
          int dd = rep * 16 + dr;
          float4 v = *(const float4*)&a.x[((size_t)b * kDim + d0 + dd) * kL + l0 + lq];
          sm.Xs[dd][lq] = v.x; sm.Xs[dd][lq + 1] = v.y;
          sm.Xs[dd][lq + 2] = v.z; sm.Xs[dd][lq + 3] = v.w;
        }
      }
      __syncthreads();
      {
        int di = (t & 15) * 4, lr = t >> 4;
#pragma unroll
        for (int rep = 0; rep < 4; ++rep) {
          int lj = rep * 16 + lr;
          ushort4 o;
          o.x = f2bf(sm.Xs[di][lj]);     o.y = f2bf(sm.Xs[di + 1][lj]);
          o.z = f2bf(sm.Xs[di + 2][lj]); o.w = f2bf(sm.Xs[di + 3][lj]);
          *(ushort4*)(a.xt + ((size_t)b * kL + l0 + lj) * kDim + d0 + di) = o;
        }
      }
    }
  }
  grid.sync();

  // ===== P1: in_proj GEMM, 1024 jobs
  for (int job = blockIdx.x; job < 1024; job += nblk) {
    const int e0 = (job & 7) * 128;
    const int l0 = ((job >> 3) & 31) * 128;
    const int b  = job >> 8;
    const unsigned short* Ab = a.xt + (size_t)b * kL * kDim;
    f32x4 acc[4][4];
#pragma unroll
    for (int i = 0; i < 4; ++i)
#pragma unroll
      for (int j = 0; j < 4; ++j) acc[i][j] = (f32x4)0.0f;
    const int srow = t >> 3, sch = t & 7;
    const int wm = wave >> 1, wn = wave & 1;
    __syncthreads();
    for (int kt = 0; kt < 4; ++kt) {
      const int k0 = kt * 64;
#pragma unroll
      for (int c = 0; c < 4; ++c) {
        int row = c * 32 + srow;
        int gch = sch ^ (row & 7);
        gload_lds16(Ab + (size_t)(l0 + row) * kDim + k0 + gch * 8,
                    (char*)sm.gin.As + c * 4096 + wave * 1024);
        gload_lds16(a.wib + (size_t)(e0 + row) * kDim + k0 + gch * 8,
                    (char*)sm.gin.Bs + c * 4096 + wave * 1024);
      }
      __syncthreads();
#pragma unroll
      for (int ks = 0; ks < 2; ++ks) {
        bf16x8 af[4], bfr[4];
#pragma unroll
        for (int f = 0; f < 4; ++f) {
          int ra = wm * 64 + f * 16 + (lane & 15);
          int ca = (ks * 4 + (lane >> 4)) ^ (ra & 7);
          af[f] = *(const bf16x8*)((const char*)sm.gin.As + ra * 128 + ca * 16);
          int rb = wn * 64 + f * 16 + (lane & 15);
          int cb = (ks * 4 + (lane >> 4)) ^ (rb & 7);
          bfr[f] = *(const bf16x8*)((const char*)sm.gin.Bs + rb * 128 + cb * 16);
        }
#pragma unroll
        for (int i = 0; i < 4; ++i)
#pragma unroll
          for (int j = 0; j < 4; ++j)
            acc[i][j] = __builtin_amdgcn_mfma_f32_16x16x32_bf16(af[i], bfr[j], acc[i][j], 0, 0, 0);
      }
      __syncthreads();
    }
    const bool is_u = (e0 < kDI);
    unsigned short* dst = is_u ? a.ubf : a.resb;
    const int ebase = is_u ? e0 : (e0 - kDI);
#pragma unroll
    for (int i = 0; i < 4; ++i)
#pragma unroll
      for (int j = 0; j < 4; ++j)
#pragma unroll
        for (int r = 0; r < 4; ++r) {
          int l = l0 + wm * 64 + i * 16 + (lane >> 4) * 4 + r;
          int e = ebase + wn * 64 + j * 16 + (lane & 15);
          dst[((size_t)b * kL + l) * kDI + e] = f2bf(acc[i][j][r]);
        }
  }
  grid.sync();

  // ===== P2a: conv + x_proj, 512 jobs (l-tile 32)
  for (int job = blockIdx.x; job < 512; job += nblk) {
    const int l0 = (job & 127) * 32;
    const int b  = job >> 7;
    const unsigned short* Ub = a.ubf + (size_t)b * kL * kDI;
    f32x4 acc[3];
#pragma unroll
    for (int i = 0; i < 3; ++i) acc[i] = (f32x4)0.0f;
    const int srow = t >> 3, sch = t & 7;
    __syncthreads();
    for (int kt = 0; kt < 8; ++kt) {
      const int k0 = kt * 64;
#pragma unroll
      for (int c = 0; c < 2; ++c) {
        int row = c * 32 + srow;
        int grow = row < 48 ? row : 47;
        int gch = sch ^ (row & 7);
        gload_lds16(a.wxb + (size_t)grow * kDI + k0 + gch * 8,
                    (char*)sm.xp.As + c * 4096 + wave * 1024);
      }
      {
        int row = srow;
        int gch = sch ^ (row & 7);
        int gl = l0 + row;
        int d0 = k0 + gch * 8;
        const unsigned short* base = Ub + (size_t)gl * kDI + d0;
        uint4 zero4 = make_uint4(0, 0, 0, 0);
        uint4 c0v = *(const uint4*)base;
        uint4 c1v = (gl >= 1) ? *(const uint4*)(base - kDI)     : zero4;
        uint4 c2v = (gl >= 2) ? *(const uint4*)(base - 2 * kDI) : zero4;
        uint4 c3v = (gl >= 3) ? *(const uint4*)(base - 3 * kDI) : zero4;
        const unsigned int* p0 = (const unsigned int*)&c0v;
        const unsigned int* p1 = (const unsigned int*)&c1v;
        const unsigned int* p2 = (const unsigned int*)&c2v;
        const unsigned int* p3 = (const unsigned int*)&c3v;
        unsigned short ov[8];
#pragma unroll
        for (int cc = 0; cc < 8; ++cc) {
          int q = cc >> 1, hi = cc & 1;
          float u0 = bf2f((unsigned short)(hi ? (p0[q] >> 16) : (p0[q] & 0xffff)));
          float u1 = bf2f((unsigned short)(hi ? (p1[q] >> 16) : (p1[q] & 0xffff)));
          float u2 = bf2f((unsigned short)(hi ? (p2[q] >> 16) : (p2[q] & 0xffff)));
          float u3 = bf2f((unsigned short)(hi ? (p3[q] >> 16) : (p3[q] & 0xffff)));
          float4 w = *(const float4*)(a.cw + (d0 + cc) * 4);
          float av = a.cb[d0 + cc] + w.x * u3 + w.y * u2 + w.z * u1 + w.w * u0;
          ov[cc] = f2bf(siluf(av));
        }
        *(uint4*)((char*)sm.xp.Bs + t * 16) = *(const uint4*)ov;
        *(uint4*)(a.ucb + ((size_t)b * kL + gl) * kDI + d0) = *(const uint4*)ov;
      }
      __syncthreads();
      if (wave < 2) {
#pragma unroll
        for (int ks = 0; ks < 2; ++ks) {
          bf16x8 af[3], bfr;
#pragma unroll
          for (int f = 0; f < 3; ++f) {
            int ra = f * 16 + (lane & 15);
            int ca = (ks * 4 + (lane >> 4)) ^ (ra & 7);
            af[f] = *(const bf16x8*)((const char*)sm.xp.As + ra * 128 + ca * 16);
          }
          int rb = wave * 16 + (lane & 15);
          int cbk = (ks * 4 + (lane >> 4)) ^ (rb & 7);
          bfr = *(const bf16x8*)((const char*)sm.xp.Bs + rb * 128 + cbk * 16);
#pragma unroll
          for (int i = 0; i < 3; ++i)
            acc[i] = __builtin_amdgcn_mfma_f32_16x16x32_bf16(af[i], bfr, acc[i], 0, 0, 0);
        }
      }
      __syncthreads();
    }
    if (wave < 2) {
      int l = l0 + wave * 16 + (lane & 15);
#pragma unroll
      for (int i = 1; i < 3; ++i)
#pragma unroll
        for (int r = 0; r < 4; ++r) {
          int m = i * 16 + (lane >> 4) * 4 + r;
          a.dbcBC[((size_t)b * 32 + (m - 16)) * kL + l] = acc[i][r];
        }
      int m0 = (lane >> 4) * 4;
      ushort4 v;
      v.x = f2bf(acc[0][0]); v.y = f2bf(acc[0][1]);
      v.z = f2bf(acc[0][2]); v.w = f2bf(acc[0][3]);
      *(ushort4*)(a.dtT + ((size_t)b * kL + l) * 32 + m0) = v;
      *(ushort4*)(a.dtT + ((size_t)b * kL + l) * 32 + 16 + m0) = make_ushort4(0, 0, 0, 0);
    }
  }
  grid.sync();

  // ===== P2b: dt_proj GEMM + softplus -> delb, 512 jobs
  for (int job = blockIdx.x; job < 512; job += nblk) {
    const int n0 = (job & 3) * 128;
    const int l0 = ((job >> 2) & 31) * 128;
    const int b  = job >> 7;
    const unsigned short* Ab = a.dtT + (size_t)b * kL * 32;
    __syncthreads();
#pragma unroll
    for (int c = 0; c < 2; ++c) {
      int unit = c * 256 + t;
      int row = unit >> 2, sc = unit & 3;
      int gch = sc ^ (row & 3);
      gload_lds16(Ab + (size_t)(l0 + row) * 32 + gch * 8,
                  (char*)sm.gdt.As + c * 4096 + t * 16);
      gload_lds16(a.wdtb + (size_t)(n0 + row) * 32 + gch * 8,
                  (char*)sm.gdt.Bs + c * 4096 + t * 16);
    }
    __syncthreads();
    f32x4 acc[4][4];
#pragma unroll
    for (int i = 0; i < 4; ++i)
#pragma unroll
      for (int j = 0; j < 4; ++j) acc[i][j] = (f32x4)0.0f;
    const int wm = wave >> 1, wn = wave & 1;
    bf16x8 af[4], bfr[4];
#pragma unroll
    for (int f = 0; f < 4; ++f) {
      int ra = wm * 64 + f * 16 + (lane & 15);
      int ca = (lane >> 4) ^ (ra & 3);
      af[f] = *(const bf16x8*)((const char*)sm.gdt.As + ra * 64 + ca * 16);
      int rb = wn * 64 + f * 16 + (lane & 15);
      int cb = (lane >> 4) ^ (rb & 3);
      bfr[f] = *(const bf16x8*)((const char*)sm.gdt.Bs + rb * 64 + cb * 16);
    }
#pragma unroll
    for (int i = 0; i < 4; ++i)
#pragma unroll
      for (int j = 0; j < 4; ++j)
        acc[i][j] = __builtin_amdgcn_mfma_f32_16x16x32_bf16(af[i], bfr[j], acc[i][j], 0, 0, 0);
#pragma unroll
    for (int j = 0; j < 4; ++j) {
      int d = n0 + wn * 64 + j * 16 + (lane & 15);
      float bd = a.bdt[d];
#pragma unroll
      for (int i = 0; i < 4; ++i)
#pragma unroll
        for (int r = 0; r < 4; ++r) {
          int l = l0 + wm * 64 + i * 16 + (lane >> 4) * 4 + r;
          float delta = softplusf(acc[i][j][r] + bd);
          a.delb[((size_t)b * kL + l) * kDI + d] = f2bf(delta);
        }
    }
  }
  grid.sync();

  // ===== P3: scanA, 512 jobs
  for (int job = blockIdx.x; job < 512; job += nblk) {
    const int dh = job & 1, ch = (job >> 1) & 63, b = job >> 7;
    const int d = dh * 256 + t;
    const int l0 = ch * kCS;
    __syncthreads();
    {
      int row = t >> 4, li = (t & 15) * 4;
      *(float4*)&sm.sa.Bsh[row][li] =
          *(const float4*)&a.dbcBC[((size_t)b * 32 + row) * kL + l0 + li];
    }
    __syncthreads();
    const bool fast = (a.flagA[0] != 0u) && (a.flagA[1] != 0u);
    const float Av0 = a.Avz[d];
    const unsigned short* pDel = a.delb + ((size_t)b * kL + l0) * kDI + d;
    const unsigned short* pU = a.ucb + ((size_t)b * kL + l0) * kDI + d;
    size_t obase = (size_t)(b * kNC + ch) * (kN * kDI) + d;
    if (fast) {
      f32x2 Sv2[8];
#pragma unroll
      for (int m = 0; m < 8; ++m) Sv2[m] = (f32x2){0.f, 0.f};
      float Pp = 1.f;
      for (int i = 0; i < kCS; i += 4) {
        f32x2 a2[4], e2[4], du2[4];
#pragma unroll
        for (int jj = 0; jj < 4; ++jj) {
          float dl = bf2f(pDel[(size_t)(i + jj) * kDI]);
          float uu = bf2f(pU[(size_t)(i + jj) * kDI]);
          float E = __expf(dl * Av0);
          float duv = dl * uu;
          du2[jj] = (f32x2){duv, duv};
          float Esq = E * E;
          a2[jj] = (f32x2){E, Esq};
          e2[jj] = (f32x2){Esq, Esq};
          Pp *= E;
        }
#pragma unroll
        for (int m = 0; m < 8; ++m) {
          float4 Ba = *(const float4*)&sm.sa.Bsh[2 * m][i];
          float4 Bb = *(const float4*)&sm.sa.Bsh[2 * m + 1][i];
          Sv2[m] = Sv2[m] * a2[0] + du2[0] * (f32x2){Ba.x, Bb.x};
          Sv2[m] = Sv2[m] * a2[1] + du2[1] * (f32x2){Ba.y, Bb.y};
          Sv2[m] = Sv2[m] * a2[2] + du2[2] * (f32x2){Ba.z, Bb.z};
          Sv2[m] = Sv2[m] * a2[3] + du2[3] * (f32x2){Ba.w, Bb.w};
          if (m < 7) {
            a2[0] *= e2[0]; a2[1] *= e2[1]; a2[2] *= e2[2]; a2[3] *= e2[3];
          }
        }
      }
      a.Pprodb[(size_t)(b * kNC + ch) * kDI + d] = Pp;
#pragma unroll
      for (int n = 0; n < kN; ++n)
        a.Sb[obase + (size_t)n * kDI] = (n & 1) ? Sv2[n >> 1].y : Sv2[n >> 1].x;
    } else {
      float Av[16];
#pragma unroll
      for (int n = 0; n < kN; ++n) Av[n] = -__expf(a.A_log[d * kN + n]);
      float Pv[16], Sv[16];
#pragma unroll
      for (int n = 0; n < kN; ++n) { Pv[n] = 1.f; Sv[n] = 0.f; }
      for (int i = 0; i < kCS; i += 4) {
        float del[4], du[4];
#pragma unroll
        for (int jj = 0; jj < 4; ++jj) {
          del[jj] = bf2f(pDel[(size_t)(i + jj) * kDI]);
          du[jj] = del[jj] * bf2f(pU[(size_t)(i + jj) * kDI]);
        }
#pragma unroll
        for (int n = 0; n < kN; ++n) {
          float4 B4 = *(const float4*)&sm.sa.Bsh[n][i];
          float v;
          v = __expf(del[0] * Av[n]); Pv[n] *= v; Sv[n] = Sv[n] * v + du[0] * B4.x;
          v = __expf(del[1] * Av[n]); Pv[n] *= v; Sv[n] = Sv[n] * v + du[1] * B4.y;
          v = __expf(del[2] * Av[n]); Pv[n] *= v; Sv[n] = Sv[n] * v + du[2] * B4.z;
          v = __expf(del[3] * Av[n]); Pv[n] *= v; Sv[n] = Sv[n] * v + du[3] * B4.w;
        }
      }
#pragma unroll
      for (int n = 0; n < kN; ++n) {
        a.Pfull[obase + (size_t)n * kDI] = Pv[n];
        a.Sb[obase + (size_t)n * kDI] = Sv[n];
      }
    }
  }
  grid.sync();

  // ===== P4: scanB, 32768 chains, grid-stride over all 256 threads
  for (int idx = blockIdx.x * 256 + t; idx < 32768; idx += nblk * 256) {
    int b = idx >> 13, nd = idx & 8191;
    int n = nd >> 9, d = nd & 511;
    size_t base = (size_t)b * kNC * 8192 + nd;
    const bool fast = (a.flagA[0] != 0u) && (a.flagA[1] != 0u);
    float carry = 0.f;
    if (fast) {
      size_t pbase = (size_t)b * kNC * kDI + d;
      const int e = n + 1;
      for (int c0 = 0; c0 < kNC; c0 += 8) {
        float p[8], s[8];
#pragma unroll
        for (int j = 0; j < 8; ++j) {
          float pr = a.Pprodb[pbase + (size_t)(c0 + j) * kDI];
          float p2 = pr * pr, p4 = p2 * p2, p8 = p4 * p4;
          float pw = 1.f;
          if (e & 1) pw *= pr;
          if (e & 2) pw *= p2;
          if (e & 4) pw *= p4;
          if (e & 8) pw *= p8;
          if (e & 16) pw *= p8 * p8;
          p[j] = pw;
          s[j] = a.Sb[base + (size_t)(c0 + j) * 8192];
        }
#pragma unroll
        for (int j = 0; j < 8; ++j) {
          a.initb[base + (size_t)(c0 + j) * 8192] = carry;
          carry = p[j] * carry + s[j];
        }
      }
    } else {
      for (int c0 = 0; c0 < kNC; c0 += 8) {
        float p[8], s[8];
#pragma unroll
        for (int j = 0; j < 8; ++j) {
          size_t o = base + (size_t)(c0 + j) * 8192;
          p[j] = a.Pfull[o]; s[j] = a.Sb[o];
        }
#pragma unroll
        for (int j = 0; j < 8; ++j) {
          a.initb[base + (size_t)(c0 + j) * 8192] = carry;
          carry = p[j] * carry + s[j];
        }
      }
    }
  }
  grid.sync();

  // ===== P5: scanC + gate, 512 jobs
  for (int job = blockIdx.x; job < 512; job += nblk) {
    const int dh = job & 1, ch = (job >> 1) & 63, b = job >> 7;
    const int d = dh * 256 + t;
    const int l0 = ch * kCS;
    __syncthreads();
    {
      int row = t >> 3, li = (t & 7) * 8;
      *(float4*)&sm.sc.BCsh[row][li] =
          *(const float4*)&a.dbcBC[((size_t)b * 32 + row) * kL + l0 + li];
      *(float4*)&sm.sc.BCsh[row][li + 4] =
          *(const float4*)&a.dbcBC[((size_t)b * 32 + row) * kL + l0 + li + 4];
    }
    __syncthreads();
    const bool fast = (a.flagA[0] != 0u) && (a.flagA[1] != 0u);
    const float Av0 = a.Avz[d];
    const float Dv = a.Dp[d];
    const unsigned short* pDel = a.delb + ((size_t)b * kL + l0) * kDI + d;
    const unsigned short* pU = a.ucb + ((size_t)b * kL + l0) * kDI + d;
    const unsigned short* pR = a.resb + ((size_t)b * kL + l0) * kDI + d;
    unsigned short* pY = a.yt + ((size_t)b * kL + l0) * kDI + d;
    size_t ibase = (size_t)(b * kNC + ch) * (kN * kDI) + d;
    if (fast) {
      f32x2 s2[8];
#pragma unroll
      for (int m = 0; m < 8; ++m)
        s2[m] = (f32x2){a.initb[ibase + (size_t)(2 * m) * kDI],
                        a.initb[ibase + (size_t)(2 * m + 1) * kDI]};
      for (int i = 0; i < kCS; i += 4) {
        float uv[4];
        f32x2 a2[4], e2[4], du2[4], yacc2[4];
#pragma unroll
        for (int jj = 0; jj < 4; ++jj) {
          float dl = bf2f(pDel[(size_t)(i + jj) * kDI]);
          uv[jj] = bf2f(pU[(size_t)(i + jj) * kDI]);
          float E = __expf(dl * Av0);
          float duv = dl * uv[jj];
          du2[jj] = (f32x2){duv, duv};
          float Esq = E * E;
          a2[jj] = (f32x2){E, Esq};
          e2[jj] = (f32x2){Esq, Esq};
          yacc2[jj] = (f32x2){0.f, 0.f};
        }
#pragma unroll
        for (int m = 0; m < 8; ++m) {
          float4 Ba = *(const float4*)&sm.sc.BCsh[2 * m][i];
          float4 Bb = *(const float4*)&sm.sc.BCsh[2 * m + 1][i];
          float4 Ca = *(const float4*)&sm.sc.BCsh[16 + 2 * m][i];
          float4 Cb = *(const float4*)&sm.sc.BCsh[16 + 2 * m + 1][i];
          s2[m] = s2[m] * a2[0] + du2[0] * (f32x2){Ba.x, Bb.x};
          yacc2[0] = yacc2[0] + s2[m] * (f32x2){Ca.x, Cb.x};
          s2[m] = s2[m] * a2[1] + du2[1] * (f32x2){Ba.y, Bb.y};
          yacc2[1] = yacc2[1] + s2[m] * (f32x2){Ca.y, Cb.y};
          s2[m] = s2[m] * a2[2] + du2[2] * (f32x2){Ba.z, Bb.z};
          yacc2[2] = yacc2[2] + s2[m] * (f32x2){Ca.z, Cb.z};
          s2[m] = s2[m] * a2[3] + du2[3] * (f32x2){Ba.w, Bb.w};
          yacc2[3] = yacc2[3] + s2[m] * (f32x2){Ca.w, Cb.w};
          if (m < 7) {
            a2[0] *= e2[0]; a2[1] *= e2[1]; a2[2] *= e2[2]; a2[3] *= e2[3];
          }
        }
#pragma unroll
        for (int jj = 0; jj < 4; ++jj) {
          float yv = yacc2[jj].x + yacc2[jj].y;
          float r = bf2f(pR[(size_t)(i + jj) * kDI]);
          float gv = (yv + uv[jj] * Dv) * siluf(r);
          pY[(size_t)(i + jj) * kDI] = f2bf(gv);
        }
      }
    } else {
      float Av[16];
#pragma unroll
      for (int n = 0; n < kN; ++n) Av[n] = -__expf(a.A_log[d * kN + n]);
      float s[16];
#pragma unroll
      for (int n = 0; n < kN; ++n) s[n] = a.initb[ibase + (size_t)n * kDI];
      for (int i = 0; i < kCS; i += 4) {
        float uv[4], du[4], del[4], yacc[4] = {0.f, 0.f, 0.f, 0.f};
#pragma unroll
        for (int jj = 0; jj < 4; ++jj) {
          del[jj] = bf2f(pDel[(size_t)(i + jj) * kDI]);
          uv[jj] = bf2f(pU[(size_t)(i + jj) * kDI]);
          du[jj] = del[jj] * uv[jj];
        }
#pragma unroll
        for (int n = 0; n < kN; ++n) {
          float4 B4 = *(const float4*)&sm.sc.BCsh[n][i];
          float4 C4 = *(const float4*)&sm.sc.BCsh[16 + n][i];
          float v;
          v = __expf(del[0] * Av[n]); s[n] = s[n] * v + du[0] * B4.x; yacc[0] += s[n] * C4.x;
          v = __expf(del[1] * Av[n]); s[n] = s[n] * v + du[1] * B4.y; yacc[1] += s[n] * C4.y;
          v = __expf(del[2] * Av[n]); s[n] = s[n] * v + du[2] * B4.z; yacc[2] += s[n] * C4.z;
          v = __expf(del[3] * Av[n]); s[n] = s[n] * v + du[3] * B4.w; yacc[3] += s[n] * C4.w;
        }
#pragma unroll
        for (int jj = 0; jj < 4; ++jj) {
          float r = bf2f(pR[(size_t)(i + jj) * kDI]);
          float gv = (yacc[jj] + uv[jj] * Dv) * siluf(r);
          pY[(size_t)(i + jj) * kDI] = f2bf(gv);
        }
      }
    }
  }
  grid.sync();

  // ===== P6: out_proj GEMM, 512 jobs (c-tile 64 x l-tile 128)
  for (int job = blockIdx.x; job < 512; job += nblk) {
    const int l0 = (job & 31) * 128;
    const int c0 = ((job >> 5) & 3) * 64;
    const int b  = job >> 7;
    const unsigned short* Bb = a.yt + (size_t)b * kL * kDI;
    f32x4 acc[2][4];
#pragma unroll
    for (int i = 0; i < 2; ++i)
#pragma unroll
      for (int j = 0; j < 4; ++j) acc[i][j] = (f32x4)0.0f;
    const int srow = t >> 3, sch = t & 7;
    const int wm = wave >> 1, wn = wave & 1;
    __syncthreads();
    for (int kt = 0; kt < 8; ++kt) {
      const int k0 = kt * 64;
#pragma unroll
      for (int c = 0; c < 2; ++c) {
        int row = c * 32 + srow;
        int gch = sch ^ (row & 7);
        gload_lds16(a.wob + (size_t)(c0 + row) * kDI + k0 + gch * 8,
                    (char*)sm.go.As + c * 4096 + wave * 1024);
      }
#pragma unroll
      for (int c = 0; c < 4; ++c) {
        int row = c * 32 + srow;
        int gch = sch ^ (row & 7);
        gload_lds16(Bb + (size_t)(l0 + row) * kDI + k0 + gch * 8,
                    (char*)sm.go.Bs + c * 4096 + wave * 1024);
      }
      __syncthreads();
#pragma unroll
      for (int ks = 0; ks < 2; ++ks) {
        bf16x8 af[2], bfr[4];
#pragma unroll
        for (int f = 0; f < 2; ++f) {
          int ra = wm * 32 + f * 16 + (lane & 15);
          int ca = (ks * 4 + (lane >> 4)) ^ (ra & 7);
          af[f] = *(const bf16x8*)((const char*)sm.go.As + ra * 128 + ca * 16);
        }
#pragma unroll
        for (int f = 0; f < 4; ++f) {
          int rb = wn * 64 + f * 16 + (lane & 15);
          int cb = (ks * 4 + (lane >> 4)) ^ (rb & 7);
          bfr[f] = *(const bf16x8*)((const char*)sm.go.Bs + rb * 128 + cb * 16);
        }
#pragma unroll
        for (int i = 0; i < 2; ++i)
#pragma unroll
          for (int j = 0; j < 4; ++j)
            acc[i][j] = __builtin_amdgcn_mfma_f32_16x16x32_bf16(af[i], bfr[j], acc[i][j], 0, 0, 0);
      }
      __syncthreads();
    }
#pragma unroll
    for (int i = 0; i < 2; ++i)
#pragma unroll
      for (int j = 0; j < 4; ++j)
#pragma unroll
        for (int r = 0; r < 4; ++r) {
          int m = c0 + wm * 32 + i * 16 + (lane >> 4) * 4 + r;
          int n = l0 + wn * 64 + j * 16 + (lane & 15);
          a.out[((size_t)b * kDim + m) * kL + n] = acc[i][j][r];
        }
  }
}

// ---------------------------------------------------------------------------
extern "C" void kernel_launch(void* const* d_in, const int* in_sizes, int n_in,
                              void* d_out, int out_size, void* d_ws, size_t ws_size,
                              hipStream_t stream) {
  const float* x       = (const float*)d_in[0];
  const float* in_w    = (const float*)d_in[1];
  const float* conv_w  = (const float*)d_in[2];
  const float* conv_b  = (const float*)d_in[3];
  const float* xproj_w = (const float*)d_in[4];
  const float* dt_w    = (const float*)d_in[5];
  const float* dt_b    = (const float*)d_in[6];
  const float* A_log   = (const float*)d_in[7];
  const float* Dp      = (const float*)d_in[8];
  const float* out_w   = (const float*)d_in[9];
  float* out = (float*)d_out;

  float* ws = (float*)d_ws;
  const size_t nBLD  = (size_t)kB * kL * kDI;                 // 8388608
  const size_t nPS   = (size_t)kB * kNC * kN * kDI;           // 2097152
  float* dbcBC  = ws;                                         // 524288 f
  float* Sb     = dbcBC + 524288;                             // nPS
  float* initb  = Sb + nPS;                                   // nPS
  float* Pprodb = initb + nPS;                                // 131072 f
  unsigned short* ubf  = (unsigned short*)(Pprodb + 131072);  // nBLD us
  unsigned short* ucb  = ubf + nBLD;
  unsigned short* resb = ucb + nBLD;
  unsigned short* delb = resb + nBLD;
  unsigned short* wib  = delb + nBLD;                         // 262144
  unsigned short* wob  = wib + 262144;                        // 131072
  unsigned short* wxb  = wob + 131072;                        // 24576
  unsigned short* wdtb = wxb + 24576;                         // 32768
  unsigned short* dtT  = wdtb + 32768;                        // 524288
  float* Avz           = (float*)(dtT + 524288);              // 512 f
  unsigned int* flagA  = (unsigned int*)(Avz + 512);          // 2 u32
  unsigned short* xt   = delb;                                // overlay
  float* Pfull         = (float*)ubf;                         // overlay
  unsigned short* yt   = (unsigned short*)ubf;                // overlay

  // Host-query path decision (deterministic, capture-safe)
  int dev = 0;
  hipGetDevice(&dev);
  int coop = 0;
  hipDeviceGetAttribute(&coop, hipDeviceAttributeCooperativeLaunch, dev);
  int numCU = 0;
  hipDeviceGetAttribute(&numCU, hipDeviceAttributeMultiprocessorCount, dev);
  if (numCU <= 0) numCU = 256;
  int maxBlk = 0;
  hipOccupancyMaxActiveBlocksPerMultiprocessor(&maxBlk, (const void*)k_mega, 256, 0);
  int grid = maxBlk * numCU;
  if (grid > 512) grid = 512;

  if (coop && grid >= 64) {
    MegaArgs a;
    a.x = x; a.w_in = in_w; a.cw = conv_w; a.cb = conv_b; a.w_x = xproj_w;
    a.w_dt = dt_w; a.bdt = dt_b; a.A_log = A_log; a.Dp = Dp; a.w_out = out_w;
    a.out = out;
    a.dbcBC = dbcBC; a.Sb = Sb; a.initb = initb; a.Pprodb = Pprodb;
    a.ubf = ubf; a.ucb = ucb; a.resb = resb; a.delb = delb;
    a.wib = wib; a.wob = wob; a.wxb = wxb; a.wdtb = wdtb; a.dtT = dtT;
    a.Avz = Avz; a.flagA = flagA; a.xt = xt; a.Pfull = Pfull; a.yt = yt;
    void* kargs[] = { (void*)&a };
    hipLaunchCooperativeKernel((const void*)k_mega, dim3(grid), dim3(256),
                               kargs, 0, stream);
    return;
  }

  // Fallback: R16 7-kernel pipeline (known-good)
  k_prep<<<dim3(2786), 256, 0, stream>>>(in_w, out_w, xproj_w, dt_w, A_log, x,
                                         wib, wob, wxb, wdtb, Avz, flagA, xt);
  gemm_in_lm<<<dim3(8, kL / 128, kB), 256, 0, stream>>>(xt, wib, ubf, resb);
  k_xproj_dt<<<dim3(kL / 64, kB), 256, 0, stream>>>(wxb, wdtb, dt_b, ubf, conv_w, conv_b,
                                                    dbcBC, ucb, delb);
  k_scanA<<<dim3(4, kNC, kB), 128, 0, stream>>>(delb, ucb, dbcBC, A_log, Avz, flagA, Pprodb, Pfull, Sb);
  k_scanB<<<dim3(kB * kDI * kN / 64), 64, 0, stream>>>(Pprodb, Pfull, Sb, flagA, initb);
  k_scanC<<<dim3(4, kNC, kB), 128, 0, stream>>>(delb, ucb, dbcBC, A_log, Avz, flagA, initb, resb, Dp, yt);
  gemm_out<<<dim3(kL / 128, kDim / 128, kB), 256, 0, stream>>>(wob, yt, out);
}

// Round 19
// 130.821 us; speedup vs baseline: 3.0285x; 3.0285x over previous
//
#include <hip/hip_runtime.h>
#include <math.h>

// Mamba block forward, l-major activations [b, l, d].
// B=4, DIM=256, L=4096, D_INNER=512, D_STATE=16, DT_RANK=16, D_CONV=4.
// R20: restore R16 (best known: 131.7us; R18/R19 coop mega-kernel regressed
// 3x -- grid.sync() is a slow software barrier on gfx950). One tweak:
// k_xproj_dt preloads the full Wdt[512][32] tile into LDS once (52KB total,
// grid=1 block/CU so occupancy unchanged) -- drops 6 staging rounds and all
// 8 intra-loop barriers in phase 2.

namespace {
constexpr int kB   = 4;
constexpr int kDim = 256;
constexpr int kL   = 4096;
constexpr int kDI  = 512;
constexpr int kN   = 16;
constexpr int kNC  = 64;   // scan chunks
constexpr int kCS  = 64;   // chunk size
} // namespace

typedef __attribute__((ext_vector_type(8))) short bf16x8;
typedef __attribute__((ext_vector_type(4))) float f32x4;
typedef __attribute__((ext_vector_type(2))) float f32x2;

__device__ __forceinline__ float rcpf(float x) { return __builtin_amdgcn_rcpf(x); }
__device__ __forceinline__ float siluf(float x) { return x * rcpf(1.f + __expf(-x)); }
__device__ __forceinline__ float softplusf(float x) {
  return fmaxf(x, 0.f) + __logf(1.f + __expf(-fabsf(x)));
}

__device__ __forceinline__ unsigned short f2bf(float x) {
  union { float f; unsigned int u; } v; v.f = x;
  unsigned int u = v.u;
  u += 0x7fffu + ((u >> 16) & 1u);   // RNE
  return (unsigned short)(u >> 16);
}
__device__ __forceinline__ float bf2f(unsigned short u) {
  union { unsigned int i; float f; } v; v.i = ((unsigned int)u) << 16; return v.f;
}

__device__ __forceinline__ void gload_lds16(const void* g, void* l) {
  __builtin_amdgcn_global_load_lds(
      (const __attribute__((address_space(1))) unsigned int*)g,
      (__attribute__((address_space(3))) unsigned int*)l, 16, 0, 0);
}

// ---------------------------------------------------------------------------
// k_prep: merged weight-convert (blocks 0..1759), A-structure check (1760-61),
// x transpose-convert (1762..2785) with float4/ushort4 access.
// ---------------------------------------------------------------------------
__global__ __launch_bounds__(256) void k_prep(const float* __restrict__ w_in,
                                              const float* __restrict__ w_out,
                                              const float* __restrict__ w_x,
                                              const float* __restrict__ w_dt,
                                              const float* __restrict__ A_log,
                                              const float* __restrict__ x,
                                              unsigned short* __restrict__ wib,
                                              unsigned short* __restrict__ wob,
                                              unsigned short* __restrict__ wxb,
                                              unsigned short* __restrict__ wdtb,
                                              float* __restrict__ Avz,
                                              unsigned int* __restrict__ flagA,
                                              unsigned short* __restrict__ xt) {
  __shared__ float Xs[64][65];
  const int blk = blockIdx.x;
  const int t = threadIdx.x;
  if (blk < 1760) {
    int idx = blk * 256 + t;
    if (idx < 262144) wib[idx] = f2bf(w_in[idx]);
    else if (idx < 393216) wob[idx - 262144] = f2bf(w_out[idx - 262144]);
    else if (idx < 417792) wxb[idx - 393216] = f2bf(w_x[idx - 393216]);
    else {
      int i = idx - 417792;           // [0, 32768)
      int r = i & 31, d = i >> 5;
      wdtb[i] = (r < 16) ? f2bf(w_dt[d * 16 + r]) : (unsigned short)0;
    }
  } else if (blk < 1762) {
    int d = (blk - 1760) * 256 + t;
    float a0 = -__expf(A_log[d * kN]);
    bool ok = true;
#pragma unroll
    for (int n = 1; n < kN; ++n) {
      float av = -__expf(A_log[d * kN + n]);
      ok = ok && (fabsf(av - (n + 1) * a0) <= 1e-5f * fabsf(av));
    }
    Avz[d] = a0;
    unsigned long long bal = __ballot(ok);
    int wv = t >> 6;
    if ((t & 63) == 0) ((unsigned long long*)Xs)[wv] = bal;
    __syncthreads();
    if (t == 0) {
      unsigned long long all = ~0ull;
#pragma unroll
      for (int w = 0; w < 4; ++w) all &= ((unsigned long long*)Xs)[w];
      flagA[blk - 1760] = (all == ~0ull) ? 1u : 0u;
    }
  } else {
    int id = blk - 1762;
    int lb = id & 63, db = (id >> 6) & 3, b = id >> 8;
    const int d0 = db * 64, l0 = lb * 64;
    {
      int lq = (t & 15) * 4;   // l offset (float4)
      int dr = t >> 4;         // d row within pass
#pragma unroll
      for (int rep = 0; rep < 4; ++rep) {
        int dd = rep * 16 + dr;
        float4 v = *(const float4*)&x[((size_t)b * kDim + d0 + dd) * kL + l0 + lq];
        Xs[dd][lq] = v.x; Xs[dd][lq + 1] = v.y;
        Xs[dd][lq + 2] = v.z; Xs[dd][lq + 3] = v.w;
      }
    }
    __syncthreads();
    {
      int di = (t & 15) * 4;   // d offset (ushort4)
      int lr = t >> 4;         // l row within pass
#pragma unroll
      for (int rep = 0; rep < 4; ++rep) {
        int lj = rep * 16 + lr;
        ushort4 o;
        o.x = f2bf(Xs[di][lj]);     o.y = f2bf(Xs[di + 1][lj]);
        o.z = f2bf(Xs[di + 2][lj]); o.w = f2bf(Xs[di + 3][lj]);
        *(ushort4*)(xt + ((size_t)b * kL + l0 + lj) * kDim + d0 + di) = o;
      }
    }
  }
}

// ---------------------------------------------------------------------------
// in_proj GEMM, l-major bf16 output.
// ---------------------------------------------------------------------------
__global__ __launch_bounds__(256) void gemm_in_lm(const unsigned short* __restrict__ xt,
                                                  const unsigned short* __restrict__ W,
                                                  unsigned short* __restrict__ ubf,
                                                  unsigned short* __restrict__ resb) {
  __shared__ __align__(16) unsigned short As[128 * 64];
  __shared__ __align__(16) unsigned short Bs[128 * 64];
  const int e0 = blockIdx.x * 128;
  const int l0 = blockIdx.y * 128;
  const int b  = blockIdx.z;
  const int t  = threadIdx.x;
  const int wave = t >> 6, lane = t & 63;
  const int wm = wave >> 1, wn = wave & 1;
  const unsigned short* Ab = xt + (size_t)b * kL * kDim;

  f32x4 acc[4][4];
#pragma unroll
  for (int i = 0; i < 4; ++i)
#pragma unroll
    for (int j = 0; j < 4; ++j) acc[i][j] = (f32x4)0.0f;

  const int srow = t >> 3, sch = t & 7;
  for (int kt = 0; kt < 4; ++kt) {
    const int k0 = kt * 64;
#pragma unroll
    for (int c = 0; c < 4; ++c) {
      int row = c * 32 + srow;
      int gch = sch ^ (row & 7);
      gload_lds16(Ab + (size_t)(l0 + row) * kDim + k0 + gch * 8,
                  (char*)As + c * 4096 + wave * 1024);
      gload_lds16(W  + (size_t)(e0 + row) * kDim + k0 + gch * 8,
                  (char*)Bs + c * 4096 + wave * 1024);
    }
    __syncthreads();
#pragma unroll
    for (int ks = 0; ks < 2; ++ks) {
      bf16x8 af[4], bfr[4];
#pragma unroll
      for (int f = 0; f < 4; ++f) {
        int ra = wm * 64 + f * 16 + (lane & 15);
        int ca = (ks * 4 + (lane >> 4)) ^ (ra & 7);
        af[f] = *(const bf16x8*)((const char*)As + ra * 128 + ca * 16);
        int rb = wn * 64 + f * 16 + (lane & 15);
        int cb = (ks * 4 + (lane >> 4)) ^ (rb & 7);
        bfr[f] = *(const bf16x8*)((const char*)Bs + rb * 128 + cb * 16);
      }
#pragma unroll
      for (int i = 0; i < 4; ++i)
#pragma unroll
        for (int j = 0; j < 4; ++j)
          acc[i][j] = __builtin_amdgcn_mfma_f32_16x16x32_bf16(af[i], bfr[j], acc[i][j], 0, 0, 0);
    }
    __syncthreads();
  }

  const bool is_u = (e0 < kDI);
  unsigned short* dst = is_u ? ubf : resb;
  const int ebase = is_u ? e0 : (e0 - kDI);
#pragma unroll
  for (int i = 0; i < 4; ++i)
#pragma unroll
    for (int j = 0; j < 4; ++j)
#pragma unroll
      for (int r = 0; r < 4; ++r) {
        int l = l0 + wm * 64 + i * 16 + (lane >> 4) * 4 + r;
        int e = ebase + wn * 64 + j * 16 + (lane & 15);
        dst[((size_t)b * kL + l) * kDI + e] = f2bf(acc[i][j][r]);
      }
}

// ---------------------------------------------------------------------------
// k_xproj_dt (l-tile 64, 256 blocks), conv fused into B-staging; Wdt tile
// preloaded whole (512x32 bf16, 32KB) -> phase 2 is barrier-free.
// ---------------------------------------------------------------------------
__global__ __launch_bounds__(256) void k_xproj_dt(const unsigned short* __restrict__ Wx,
                                                  const unsigned short* __restrict__ Wdtb,
                                                  const float* __restrict__ bdt,
                                                  const unsigned short* __restrict__ ubf,
                                                  const float* __restrict__ cw,
                                                  const float* __restrict__ cb,
                                                  float* __restrict__ dbcBC,
                                                  unsigned short* __restrict__ ucb,
                                                  unsigned short* __restrict__ delb) {
  __shared__ __align__(16) unsigned short As[64 * 64];
  __shared__ __align__(16) unsigned short Bs[64 * 64];
  __shared__ __align__(16) unsigned short dtTl[64 * 32];
  __shared__ __align__(16) unsigned short Wl[512 * 32];
  const int l0 = blockIdx.x * 64;
  const int b  = blockIdx.y;
  const int t  = threadIdx.x;
  const int wave = t >> 6, lane = t & 63;
  const unsigned short* Ub = ubf + (size_t)b * kL * kDI;

  // preload Wdt [512][32] into Wl (8 x 256 threads x 16B)
#pragma unroll
  for (int c2 = 0; c2 < 8; ++c2) {
    int unit = c2 * 256 + t;
    int row = unit >> 2, sc = unit & 3;
    int gch = sc ^ (row & 3);
    gload_lds16(Wdtb + (size_t)row * 32 + gch * 8,
                (char*)Wl + c2 * 4096 + t * 16);
  }

  f32x4 acc[3];
#pragma unroll
  for (int i = 0; i < 3; ++i) acc[i] = (f32x4)0.0f;

  const int srow = t >> 3, sch = t & 7;
  for (int kt = 0; kt < 8; ++kt) {
    const int k0 = kt * 64;
#pragma unroll
    for (int c = 0; c < 2; ++c) {
      int row = c * 32 + srow;
      int grow = row < 48 ? row : 47;
      int gch = sch ^ (row & 7);
      gload_lds16(Wx + (size_t)grow * kDI + k0 + gch * 8,
                  (char*)As + c * 4096 + wave * 1024);
    }
    // B staging: compute uc = silu(conv(ubf)) for (gl, d0..d0+8)
#pragma unroll
    for (int c = 0; c < 2; ++c) {
      int row = c * 32 + srow;
      int gch = sch ^ (row & 7);
      int gl = l0 + row;
      int d0 = k0 + gch * 8;
      const unsigned short* base = Ub + (size_t)gl * kDI + d0;
      uint4 zero4 = make_uint4(0, 0, 0, 0);
      uint4 c0v = *(const uint4*)base;
      uint4 c1v = (gl >= 1) ? *(const uint4*)(base - kDI)     : zero4;
      uint4 c2v = (gl >= 2) ? *(const uint4*)(base - 2 * kDI) : zero4;
      uint4 c3v = (gl >= 3) ? *(const uint4*)(base - 3 * kDI) : zero4;
      const unsigned int* p0 = (const unsigned int*)&c0v;
      const unsigned int* p1 = (const unsigned int*)&c1v;
      const unsigned int* p2 = (const unsigned int*)&c2v;
      const unsigned int* p3 = (const unsigned int*)&c3v;
      unsigned short ov[8];
#pragma unroll
      for (int cc = 0; cc < 8; ++cc) {
        int q = cc >> 1, hi = cc & 1;
        float u0 = bf2f((unsigned short)(hi ? (p0[q] >> 16) : (p0[q] & 0xffff)));
        float u1 = bf2f((unsigned short)(hi ? (p1[q] >> 16) : (p1[q] & 0xffff)));
        float u2 = bf2f((unsigned short)(hi ? (p2[q] >> 16) : (p2[q] & 0xffff)));
        float u3 = bf2f((unsigned short)(hi ? (p3[q] >> 16) : (p3[q] & 0xffff)));
        float4 w = *(const float4*)(cw + (d0 + cc) * 4);
        float a = cb[d0 + cc] + w.x * u3 + w.y * u2 + w.z * u1 + w.w * u0;
        ov[cc] = f2bf(siluf(a));
      }
      *(uint4*)((char*)Bs + c * 4096 + t * 16) = *(const uint4*)ov;  // LDS slot
      *(uint4*)(ucb + ((size_t)b * kL + gl) * kDI + d0) = *(const uint4*)ov;
    }
    __syncthreads();
#pragma unroll
    for (int ks = 0; ks < 2; ++ks) {
      bf16x8 af[3], bfr;
#pragma unroll
      for (int f = 0; f < 3; ++f) {
        int ra = f * 16 + (lane & 15);
        int ca = (ks * 4 + (lane >> 4)) ^ (ra & 7);
        af[f] = *(const bf16x8*)((const char*)As + ra * 128 + ca * 16);
      }
      int rb = wave * 16 + (lane & 15);
      int cbk = (ks * 4 + (lane >> 4)) ^ (rb & 7);
      bfr = *(const bf16x8*)((const char*)Bs + rb * 128 + cbk * 16);
#pragma unroll
      for (int i = 0; i < 3; ++i)
        acc[i] = __builtin_amdgcn_mfma_f32_16x16x32_bf16(af[i], bfr, acc[i], 0, 0, 0);
    }
    __syncthreads();
  }

  // phase-1 epilogue: B/C rows -> global; dt rows -> LDS (swizzled)
#pragma unroll
  for (int i = 1; i < 3; ++i)
#pragma unroll
    for (int r = 0; r < 4; ++r) {
      int m = i * 16 + (lane >> 4) * 4 + r;
      int l = l0 + wave * 16 + (lane & 15);
      dbcBC[((size_t)b * 32 + (m - 16)) * kL + l] = acc[i][r];
    }
  {
    int lloc = wave * 16 + (lane & 15);
    int m0 = (lane >> 4) * 4;
    ushort4 v;
    v.x = f2bf(acc[0][0]); v.y = f2bf(acc[0][1]);
    v.z = f2bf(acc[0][2]); v.w = f2bf(acc[0][3]);
    int byte = lloc * 64 + (((m0 >> 3) ^ (lloc & 3)) << 4) + ((m0 & 7) << 1);
    *(ushort4*)((char*)dtTl + byte) = v;
  }
  if (t < 128) {
    int lz = t >> 1, zc = 2 + (t & 1);          // zero K-pad chunks 2,3
    *(uint4*)((char*)dtTl + lz * 64 + ((zc ^ (lz & 3)) << 4)) = make_uint4(0, 0, 0, 0);
  }
  __syncthreads();

  // phase 2: dt_proj over 4 d-tiles of 128 -- no staging, no barriers
  for (int dt4 = 0; dt4 < 4; ++dt4) {
    f32x4 acc2[4][2];
#pragma unroll
    for (int i = 0; i < 4; ++i)
#pragma unroll
      for (int j = 0; j < 2; ++j) acc2[i][j] = (f32x4)0.0f;
    bf16x8 afr[4], bfr2[2];
#pragma unroll
    for (int f = 0; f < 4; ++f) {
      int ra = f * 16 + (lane & 15);   // l row (0..63)
      afr[f] = *(const bf16x8*)((const char*)dtTl + ra * 64 + (((lane >> 4) ^ (ra & 3)) << 4));
    }
#pragma unroll
    for (int f = 0; f < 2; ++f) {
      int rb = dt4 * 128 + wave * 32 + f * 16 + (lane & 15);   // d row (0..511)
      bfr2[f] = *(const bf16x8*)((const char*)Wl + rb * 64 + (((lane >> 4) ^ (rb & 3)) << 4));
    }
#pragma unroll
    for (int i = 0; i < 4; ++i)
#pragma unroll
      for (int j = 0; j < 2; ++j)
        acc2[i][j] = __builtin_amdgcn_mfma_f32_16x16x32_bf16(afr[i], bfr2[j], acc2[i][j], 0, 0, 0);
#pragma unroll
    for (int j = 0; j < 2; ++j) {
      int d = dt4 * 128 + wave * 32 + j * 16 + (lane & 15);
      float bd = bdt[d];
#pragma unroll
      for (int i = 0; i < 4; ++i)
#pragma unroll
        for (int r = 0; r < 4; ++r) {
          int l = l0 + i * 16 + (lane >> 4) * 4 + r;
          float delta = softplusf(acc2[i][j][r] + bd);
          delb[((size_t)b * kL + l) * kDI + d] = f2bf(delta);
        }
    }
  }
}

// ---------------------------------------------------------------------------
// Scan phase A (128 threads, CS=64): reads delta/u bf16; E=exp(delta*Av0);
// packed n-loop. Fast: scalar Pprod + S. Generic: full P + S.
// ---------------------------------------------------------------------------
__global__ __launch_bounds__(128) void k_scanA(const unsigned short* __restrict__ delb,
                                               const unsigned short* __restrict__ ucb,
                                               const float* __restrict__ dbcBC,
                                               const float* __restrict__ A_log,
                                               const float* __restrict__ Avz,
                                               const unsigned int* __restrict__ flagA,
                                               float* __restrict__ Pprod,
                                               float* __restrict__ Pfull,
                                               float* __restrict__ S) {
  __shared__ __align__(16) float Bsh[16][kCS];
  const int b = blockIdx.z, ch = blockIdx.y;
  const int t = threadIdx.x;
  const int d = blockIdx.x * 128 + t;
  const int l0 = ch * kCS;
  {
    int row = t >> 3, li = (t & 7) * 8;
    *(float4*)&Bsh[row][li] =
        *(const float4*)&dbcBC[((size_t)b * 32 + row) * kL + l0 + li];
    *(float4*)&Bsh[row][li + 4] =
        *(const float4*)&dbcBC[((size_t)b * 32 + row) * kL + l0 + li + 4];
  }
  __syncthreads();
  const bool fast = (flagA[0] != 0u) && (flagA[1] != 0u);
  const float Av0 = Avz[d];
  const unsigned short* pDel = delb + ((size_t)b * kL + l0) * kDI + d;
  const unsigned short* pU = ucb + ((size_t)b * kL + l0) * kDI + d;
  size_t obase = (size_t)(b * kNC + ch) * (kN * kDI) + d;

  if (fast) {
    f32x2 Sv2[8];
#pragma unroll
    for (int m = 0; m < 8; ++m) Sv2[m] = (f32x2){0.f, 0.f};
    float Pp = 1.f;
    for (int i = 0; i < kCS; i += 4) {
      f32x2 a2[4], e2[4], du2[4];
#pragma unroll
      for (int jj = 0; jj < 4; ++jj) {
        float dl = bf2f(pDel[(size_t)(i + jj) * kDI]);
        float uu = bf2f(pU[(size_t)(i + jj) * kDI]);
        float E = __expf(dl * Av0);
        float duv = dl * uu;
        du2[jj] = (f32x2){duv, duv};
        float Esq = E * E;
        a2[jj] = (f32x2){E, Esq};
        e2[jj] = (f32x2){Esq, Esq};
        Pp *= E;
      }
#pragma unroll
      for (int m = 0; m < 8; ++m) {
        float4 Ba = *(const float4*)&Bsh[2 * m][i];
        float4 Bb = *(const float4*)&Bsh[2 * m + 1][i];
        Sv2[m] = Sv2[m] * a2[0] + du2[0] * (f32x2){Ba.x, Bb.x};
        Sv2[m] = Sv2[m] * a2[1] + du2[1] * (f32x2){Ba.y, Bb.y};
        Sv2[m] = Sv2[m] * a2[2] + du2[2] * (f32x2){Ba.z, Bb.z};
        Sv2[m] = Sv2[m] * a2[3] + du2[3] * (f32x2){Ba.w, Bb.w};
        if (m < 7) {
          a2[0] *= e2[0]; a2[1] *= e2[1]; a2[2] *= e2[2]; a2[3] *= e2[3];
        }
      }
    }
    Pprod[(size_t)(b * kNC + ch) * kDI + d] = Pp;
#pragma unroll
    for (int n = 0; n < kN; ++n)
      S[obase + (size_t)n * kDI] = (n & 1) ? Sv2[n >> 1].y : Sv2[n >> 1].x;
  } else {
    float Av[16];
#pragma unroll
    for (int n = 0; n < kN; ++n) Av[n] = -__expf(A_log[d * kN + n]);
    float Pv[16], Sv[16];
#pragma unroll
    for (int n = 0; n < kN; ++n) { Pv[n] = 1.f; Sv[n] = 0.f; }
    for (int i = 0; i < kCS; i += 4) {
      float del[4], du[4];
#pragma unroll
      for (int jj = 0; jj < 4; ++jj) {
        del[jj] = bf2f(pDel[(size_t)(i + jj) * kDI]);
        du[jj] = del[jj] * bf2f(pU[(size_t)(i + jj) * kDI]);
      }
#pragma unroll
      for (int n = 0; n < kN; ++n) {
        float4 B4 = *(const float4*)&Bsh[n][i];
        float a;
        a = __expf(del[0] * Av[n]); Pv[n] *= a; Sv[n] = Sv[n] * a + du[0] * B4.x;
        a = __expf(del[1] * Av[n]); Pv[n] *= a; Sv[n] = Sv[n] * a + du[1] * B4.y;
        a = __expf(del[2] * Av[n]); Pv[n] *= a; Sv[n] = Sv[n] * a + du[2] * B4.z;
        a = __expf(del[3] * Av[n]); Pv[n] *= a; Sv[n] = Sv[n] * a + du[3] * B4.w;
      }
    }
#pragma unroll
    for (int n = 0; n < kN; ++n) {
      Pfull[obase + (size_t)n * kDI] = Pv[n];
      S[obase + (size_t)n * kDI] = Sv[n];
    }
  }
}

// ---------------------------------------------------------------------------
// Scan phase B (64 threads x 512 blocks): combine chunk summaries.
// ---------------------------------------------------------------------------
__global__ __launch_bounds__(64) void k_scanB(const float* __restrict__ Pprod,
                                              const float* __restrict__ Pfull,
                                              const float* __restrict__ S,
                                              const unsigned int* __restrict__ flagA,
                                              float* __restrict__ init) {
  int idx = blockIdx.x * 64 + threadIdx.x;  // b*8192 + n*512 + d
  int b = idx >> 13, nd = idx & 8191;
  int n = nd >> 9, d = nd & 511;
  size_t base = (size_t)b * kNC * 8192 + nd;
  const bool fast = (flagA[0] != 0u) && (flagA[1] != 0u);
  float carry = 0.f;
  if (fast) {
    size_t pbase = (size_t)b * kNC * kDI + d;
    const int e = n + 1;
    for (int c0 = 0; c0 < kNC; c0 += 8) {
      float p[8], s[8];
#pragma unroll
      for (int j = 0; j < 8; ++j) {
        float pr = Pprod[pbase + (size_t)(c0 + j) * kDI];
        float p2 = pr * pr, p4 = p2 * p2, p8 = p4 * p4;
        float pw = 1.f;
        if (e & 1) pw *= pr;
        if (e & 2) pw *= p2;
        if (e & 4) pw *= p4;
        if (e & 8) pw *= p8;
        if (e & 16) pw *= p8 * p8;
        p[j] = pw;
        s[j] = S[base + (size_t)(c0 + j) * 8192];
      }
#pragma unroll
      for (int j = 0; j < 8; ++j) {
        init[base + (size_t)(c0 + j) * 8192] = carry;
        carry = p[j] * carry + s[j];
      }
    }
  } else {
    for (int c0 = 0; c0 < kNC; c0 += 8) {
      float p[8], s[8];
#pragma unroll
      for (int j = 0; j < 8; ++j) {
        size_t o = base + (size_t)(c0 + j) * 8192;
        p[j] = Pfull[o]; s[j] = S[o];
      }
#pragma unroll
      for (int j = 0; j < 8; ++j) {
        init[base + (size_t)(c0 + j) * 8192] = carry;
        carry = p[j] * carry + s[j];
      }
    }
  }
}

// ---------------------------------------------------------------------------
// Scan phase C (+gate, 128 threads, CS=64): E/du recomputed; packed n-loop;
// g=(y+u*D)*silu(res) -> yt bf16.
// ---------------------------------------------------------------------------
__global__ __launch_bounds__(128) void k_scanC(const unsigned short* __restrict__ delb,
                                               const unsigned short* __restrict__ ucb,
                                               const float* __restrict__ dbcBC,
                                               const float* __restrict__ A_log,
                                               const float* __restrict__ Avz,
                                               const unsigned int* __restrict__ flagA,
                                               const float* __restrict__ init,
                                               const unsigned short* __restrict__ resb,
                                               const float* __restrict__ Dp,
                                               unsigned short* __restrict__ yt) {
  __shared__ __align__(16) float BCsh[32][kCS];  // 0-15 B, 16-31 C
  const int b = blockIdx.z, ch = blockIdx.y;
  const int t = threadIdx.x;
  const int d = blockIdx.x * 128 + t;
  const int l0 = ch * kCS;
  {
    int row = t >> 2, li = (t & 3) * 16;
#pragma unroll
    for (int q = 0; q < 4; ++q)
      *(float4*)&BCsh[row][li + q * 4] =
          *(const float4*)&dbcBC[((size_t)b * 32 + row) * kL + l0 + li + q * 4];
  }
  __syncthreads();
  const bool fast = (flagA[0] != 0u) && (flagA[1] != 0u);
  const float Av0 = Avz[d];
  const float Dv = Dp[d];
  const unsigned short* pDel = delb + ((size_t)b * kL + l0) * kDI + d;
  const unsigned short* pU = ucb + ((size_t)b * kL + l0) * kDI + d;
  const unsigned short* pR = resb + ((size_t)b * kL + l0) * kDI + d;
  unsigned short* pY = yt + ((size_t)b * kL + l0) * kDI + d;
  size_t ibase = (size_t)(b * kNC + ch) * (kN * kDI) + d;

  if (fast) {
    f32x2 s2[8];
#pragma unroll
    for (int m = 0; m < 8; ++m)
      s2[m] = (f32x2){init[ibase + (size_t)(2 * m) * kDI],
                      init[ibase + (size_t)(2 * m + 1) * kDI]};
    for (int i = 0; i < kCS; i += 4) {
      float uv[4];
      f32x2 a2[4], e2[4], du2[4], yacc2[4];
#pragma unroll
      for (int jj = 0; jj < 4; ++jj) {
        float dl = bf2f(pDel[(size_t)(i + jj) * kDI]);
        uv[jj] = bf2f(pU[(size_t)(i + jj) * kDI]);
        float E = __expf(dl * Av0);
        float duv = dl * uv[jj];
        du2[jj] = (f32x2){duv, duv};
        float Esq = E * E;
        a2[jj] = (f32x2){E, Esq};
        e2[jj] = (f32x2){Esq, Esq};
        yacc2[jj] = (f32x2){0.f, 0.f};
      }
#pragma unroll
      for (int m = 0; m < 8; ++m) {
        float4 Ba = *(const float4*)&BCsh[2 * m][i];
        float4 Bb = *(const float4*)&BCsh[2 * m + 1][i];
        float4 Ca = *(const float4*)&BCsh[16 + 2 * m][i];
        float4 Cb = *(const float4*)&BCsh[16 + 2 * m + 1][i];
        s2[m] = s2[m] * a2[0] + du2[0] * (f32x2){Ba.x, Bb.x};
        yacc2[0] = yacc2[0] + s2[m] * (f32x2){Ca.x, Cb.x};
        s2[m] = s2[m] * a2[1] + du2[1] * (f32x2){Ba.y, Bb.y};
        yacc2[1] = yacc2[1] + s2[m] * (f32x2){Ca.y, Cb.y};
        s2[m] = s2[m] * a2[2] + du2[2] * (f32x2){Ba.z, Bb.z};
        yacc2[2] = yacc2[2] + s2[m] * (f32x2){Ca.z, Cb.z};
        s2[m] = s2[m] * a2[3] + du2[3] * (f32x2){Ba.w, Bb.w};
        yacc2[3] = yacc2[3] + s2[m] * (f32x2){Ca.w, Cb.w};
        if (m < 7) {
          a2[0] *= e2[0]; a2[1] *= e2[1]; a2[2] *= e2[2]; a2[3] *= e2[3];
        }
      }
#pragma unroll
      for (int jj = 0; jj < 4; ++jj) {
        float yv = yacc2[jj].x + yacc2[jj].y;
        float r = bf2f(pR[(size_t)(i + jj) * kDI]);
        float gv = (yv + uv[jj] * Dv) * siluf(r);
        pY[(size_t)(i + jj) * kDI] = f2bf(gv);
      }
    }
  } else {
    float Av[16];
#pragma unroll
    for (int n = 0; n < kN; ++n) Av[n] = -__expf(A_log[d * kN + n]);
    float s[16];
#pragma unroll
    for (int n = 0; n < kN; ++n) s[n] = init[ibase + (size_t)n * kDI];
    for (int i = 0; i < kCS; i += 4) {
      float uv[4], du[4], del[4], yacc[4] = {0.f, 0.f, 0.f, 0.f};
#pragma unroll
      for (int jj = 0; jj < 4; ++jj) {
        del[jj] = bf2f(pDel[(size_t)(i + jj) * kDI]);
        uv[jj] = bf2f(pU[(size_t)(i + jj) * kDI]);
        du[jj] = del[jj] * uv[jj];
      }
#pragma unroll
      for (int n = 0; n < kN; ++n) {
        float4 B4 = *(const float4*)&BCsh[n][i];
        float4 C4 = *(const float4*)&BCsh[16 + n][i];
        float a;
        a = __expf(del[0] * Av[n]); s[n] = s[n] * a + du[0] * B4.x; yacc[0] += s[n] * C4.x;
        a = __expf(del[1] * Av[n]); s[n] = s[n] * a + du[1] * B4.y; yacc[1] += s[n] * C4.y;
        a = __expf(del[2] * Av[n]); s[n] = s[n] * a + du[2] * B4.z; yacc[2] += s[n] * C4.z;
        a = __expf(del[3] * Av[n]); s[n] = s[n] * a + du[3] * B4.w; yacc[3] += s[n] * C4.w;
      }
#pragma unroll
      for (int jj = 0; jj < 4; ++jj) {
        float r = bf2f(pR[(size_t)(i + jj) * kDI]);
        float gv = (yacc[jj] + uv[jj] * Dv) * siluf(r);
        pY[(size_t)(i + jj) * kDI] = f2bf(gv);
      }
    }
  }
}

// ---------------------------------------------------------------------------
// out_proj GEMM: out[b][c][l] = sum_k Wo[c,k] * yt[b,l,k].
// ---------------------------------------------------------------------------
__global__ __launch_bounds__(256) void gemm_out(const unsigned short* __restrict__ A,
                                                const unsigned short* __restrict__ Bt,
                                                float* __restrict__ C0) {
  __shared__ __align__(16) unsigned short As[128 * 64];
  __shared__ __align__(16) unsigned short Bs[128 * 64];
  const int n0 = blockIdx.x * 128;
  const int m0 = blockIdx.y * 128;
  const int b  = blockIdx.z;
  const int t  = threadIdx.x;
  const int wave = t >> 6, lane = t & 63;
  const int wm = wave >> 1, wn = wave & 1;
  const unsigned short* Bb = Bt + (size_t)b * kL * kDI;

  f32x4 acc[4][4];
#pragma unroll
  for (int i = 0; i < 4; ++i)
#pragma unroll
    for (int j = 0; j < 4; ++j) acc[i][j] = (f32x4)0.0f;

  const int srow = t >> 3, sch = t & 7;
  for (int kt = 0; kt < 8; ++kt) {
    const int k0 = kt * 64;
#pragma unroll
    for (int c = 0; c < 4; ++c) {
      int row = c * 32 + srow;
      int gch = sch ^ (row & 7);
      gload_lds16(A  + (size_t)(m0 + row) * kDI + k0 + gch * 8,
                  (char*)As + c * 4096 + wave * 1024);
      gload_lds16(Bb + (size_t)(n0 + row) * kDI + k0 + gch * 8,
                  (char*)Bs + c * 4096 + wave * 1024);
    }
    __syncthreads();
#pragma unroll
    for (int ks = 0; ks < 2; ++ks) {
      bf16x8 af[4], bfr[4];
#pragma unroll
      for (int f = 0; f < 4; ++f) {
        int ra = wm * 64 + f * 16 + (lane & 15);
        int ca = (ks * 4 + (lane >> 4)) ^ (ra & 7);
        af[f] = *(const bf16x8*)((const char*)As + ra * 128 + ca * 16);
        int rb = wn * 64 + f * 16 + (lane & 15);
        int cb = (ks * 4 + (lane >> 4)) ^ (rb & 7);
        bfr[f] = *(const bf16x8*)((const char*)Bs + rb * 128 + cb * 16);
      }
#pragma unroll
      for (int i = 0; i < 4; ++i)
#pragma unroll
        for (int j = 0; j < 4; ++j)
          acc[i][j] = __builtin_amdgcn_mfma_f32_16x16x32_bf16(af[i], bfr[j], acc[i][j], 0, 0, 0);
    }
    __syncthreads();
  }
#pragma unroll
  for (int i = 0; i < 4; ++i)
#pragma unroll
    for (int j = 0; j < 4; ++j)
#pragma unroll
      for (int r = 0; r < 4; ++r) {
        int m = m0 + wm * 64 + i * 16 + (lane >> 4) * 4 + r;
        int n = n0 + wn * 64 + j * 16 + (lane & 15);
        C0[((size_t)b * kDim + m) * kL + n] = acc[i][j][r];
      }
}

// ---------------------------------------------------------------------------
extern "C" void kernel_launch(void* const* d_in, const int* in_sizes, int n_in,
                              void* d_out, int out_size, void* d_ws, size_t ws_size,
                              hipStream_t stream) {
  const float* x       = (const float*)d_in[0];
  const float* in_w    = (const float*)d_in[1];
  const float* conv_w  = (const float*)d_in[2];
  const float* conv_b  = (const float*)d_in[3];
  const float* xproj_w = (const float*)d_in[4];
  const float* dt_w    = (const float*)d_in[5];
  const float* dt_b    = (const float*)d_in[6];
  const float* A_log   = (const float*)d_in[7];
  const float* Dp      = (const float*)d_in[8];
  const float* out_w   = (const float*)d_in[9];
  float* out = (float*)d_out;

  // workspace layout (~84 MB)
  float* ws = (float*)d_ws;
  const size_t nBLD  = (size_t)kB * kL * kDI;                 // 8388608
  const size_t nPS   = (size_t)kB * kNC * kN * kDI;           // 2097152
  float* dbcBC  = ws;                                         // 524288 f
  float* Sb     = dbcBC + 524288;                             // nPS
  float* initb  = Sb + nPS;                                   // nPS
  float* Pprodb = initb + nPS;                                // 131072 f
  unsigned short* ubf  = (unsigned short*)(Pprodb + 131072);  // nBLD us
  unsigned short* ucb  = ubf + nBLD;                          // nBLD us
  unsigned short* resb = ucb + nBLD;                          // nBLD us
  unsigned short* delb = resb + nBLD;                         // nBLD us
  unsigned short* wib  = delb + nBLD;                         // 262144
  unsigned short* wob  = wib + 262144;                        // 131072
  unsigned short* wxb  = wob + 131072;                        // 24576
  unsigned short* wdtb = wxb + 24576;                         // 32768
  float* Avz           = (float*)(wdtb + 32768);              // 512 f
  unsigned int* flagA  = (unsigned int*)(Avz + 512);          // 2 u32
  unsigned short* xt   = delb;                                // overlay: dead before k_xproj_dt
  float* Pfull         = (float*)ubf;                         // overlay: ubf dead after k_xproj_dt
  unsigned short* yt   = (unsigned short*)ubf;                // overlay: Pfull dead after scanB

  k_prep<<<dim3(2786), 256, 0, stream>>>(in_w, out_w, xproj_w, dt_w, A_log, x,
                                         wib, wob, wxb, wdtb, Avz, flagA, xt);
  gemm_in_lm<<<dim3(8, kL / 128, kB), 256, 0, stream>>>(xt, wib, ubf, resb);
  k_xproj_dt<<<dim3(kL / 64, kB), 256, 0, stream>>>(wxb, wdtb, dt_b, ubf, conv_w, conv_b,
                                                    dbcBC, ucb, delb);
  k_scanA<<<dim3(4, kNC, kB), 128, 0, stream>>>(delb, ucb, dbcBC, A_log, Avz, flagA, Pprodb, Pfull, Sb);
  k_scanB<<<dim3(kB * kDI * kN / 64), 64, 0, stream>>>(Pprodb, Pfull, Sb, flagA, initb);
  k_scanC<<<dim3(4, kNC, kB), 128, 0, stream>>>(delb, ucb, dbcBC, A_log, Avz, flagA, initb, resb, Dp, yt);
  gemm_out<<<dim3(kL / 128, kDim / 128, kB), 256, 0, stream>>>(wob, yt, out);
}